// Round 13
// baseline (741.408 us; speedup 1.0000x reference)
//
#include <hip/hip_runtime.h>
#include <cstddef>
#include <cstdint>

#define LRr 0.02f

typedef unsigned short u16;
typedef __attribute__((ext_vector_type(8))) __bf16 bf16x8;
typedef __attribute__((ext_vector_type(8))) short short8;
typedef __attribute__((ext_vector_type(4))) float f32x4;
typedef __attribute__((ext_vector_type(4))) u16 u16x4;

static __device__ __forceinline__ u16 f2bf(float f) {
  union { float f; unsigned int u; } v{f};
  unsigned int r = (v.u + 0x7FFFu + ((v.u >> 16) & 1u)) >> 16;
  return (u16)r;
}
static __device__ __forceinline__ float bf2f(u16 h) {
  union { unsigned int u; float f; } v{(unsigned int)h << 16};
  return v.f;
}

static __device__ __forceinline__ void gload_lds16(const void* g, void* l) {
  __builtin_amdgcn_global_load_lds(
      (const __attribute__((address_space(1))) unsigned int*)g,
      (__attribute__((address_space(3))) unsigned int*)l, 16, 0, 0);
}

// counted waitcnt: allow N outstanding VMEM ops
template<int N> static __device__ __forceinline__ void wait_vm() {
  if constexpr (N <= 0)      asm volatile("s_waitcnt vmcnt(0)" ::: "memory");
  else if constexpr (N == 1) asm volatile("s_waitcnt vmcnt(1)" ::: "memory");
  else if constexpr (N == 2) asm volatile("s_waitcnt vmcnt(2)" ::: "memory");
  else if constexpr (N == 3) asm volatile("s_waitcnt vmcnt(3)" ::: "memory");
  else if constexpr (N == 4) asm volatile("s_waitcnt vmcnt(4)" ::: "memory");
  else                       asm volatile("s_waitcnt vmcnt(6)" ::: "memory");
}
static __device__ __forceinline__ void barrier_mem() {
  asm volatile("s_barrier" ::: "memory");
}

enum { EP_RAW = 0, EP_E1 = 1, EP_E2 = 2, EP_P2 = 3, EP_P3 = 4 };

// Implicit-GEMM 3x3 conv, pad=1, NHWC bf16 — 512-thread / 8-wave blocks.
// B triple-buffered per CS-chunk via global_load_lds + counted vmcnt(BR) +
// raw s_barrier (r11-verified). r13: p2/ff2 use 4x4 frags/wave (32.7 FLOP per
// LDS byte vs 21.8) to lift the measured LDS-BW ceiling.
template<int H, int CIN, int COUT, int WAVES_M, int WAVES_N, int WN, int NBLK,
         int CS, int IMGS, int EPI, bool STATS>
__device__ __forceinline__ void gemm_body(
    int bid, char* lds,
    const u16* __restrict__ in, const u16* __restrict__ wpk,
    float* __restrict__ fout, u16* __restrict__ bout,
    const u16* __restrict__ aux, float* __restrict__ sums)
{
  constexpr int P = H * H, W = H;
  constexpr int LW = (H == 16) ? 4 : ((H == 8) ? 3 : 2);
  constexpr bool HALO = (IMGS == 1);
  constexpr int MROWS = IMGS * P;
  constexpr int WM = MROWS / WAVES_M;
  constexpr int M_rep = WM / 16, N_rep = WN / 16;
  constexpr int COB = WAVES_N * WN;
  constexpr int PW = H + 2;
  constexpr int ASZ = HALO ? PW * PW * CIN * 2 : MROWS * CIN * 2;
  constexpr int BCH = CS * COB * 2;
  constexpr int CH = CIN / CS;
  constexpr int NS = 9 * CH;
  constexpr int BR = (CS * COB) / 4096;
  static_assert(COB * NBLK == COUT, "n");
  static_assert(WAVES_M * WAVES_N == 8, "w");
  static_assert(ASZ + 3 * BCH <= 163840, "lds");
  static_assert((CS * COB) % 4096 == 0, "br");

  const int tid = threadIdx.x;
  const int l = tid & 63, l15 = l & 15, lq = l >> 4;
  const int wid = tid >> 6;
  const int wn = wid % WAVES_N, wm = wid / WAVES_N;
  const int img0 = (bid / NBLK) * IMGS;
  const int half = bid % NBLK;
  const int co0b = half * COB;
  const int wm0 = wm * WM;
  const int co = co0b + wn * WN;

  auto stageB = [&](int buf, int s) {
    int tap = s / CH, ch = s % CH;
#pragma unroll
    for (int r = 0; r < BR; ++r) {
      int j = r * 512 + tid;
      int ci8 = ch * (CS / 8) + j / COB, c = j % COB;
      const char* gp = (const char*)wpk +
          ((size_t)((tap * (CIN / 8) + ci8) * COUT + co0b + c) << 4);
      char* lp = lds + ASZ + buf * BCH + ((r * 512 + (tid & 448)) << 4);
      gload_lds16(gp, lp);
    }
  };

  stageB(0, 0);
  stageB(1, 1);

  if constexpr (HALO) {
    for (int i = tid * 16; i < ASZ; i += 8192)
      *(int4*)(lds + i) = make_int4(0, 0, 0, 0);
    __syncthreads();
    constexpr int NCH = P * CIN / 8;
    for (int i = tid; i < NCH; i += 512) {
      int pix = i / (CIN / 8), c8 = i % (CIN / 8);
      const char* gp = (const char*)in + (((size_t)img0 * P + pix) * CIN + c8 * 8) * 2;
      int cell = ((pix >> LW) + 1) * PW + (pix & (W - 1)) + 1;
      int lb = ((cell * CIN + c8 * 8) << 1) ^ ((cell & 7) << 4);
      *(short8*)(lds + lb) = *(const short8*)gp;
    }
  } else {
    constexpr int NCH = MROWS * CIN / 8;
    for (int i = tid; i < NCH; i += 512) {
      int row = i / (CIN / 8), c8 = i % (CIN / 8);
      const char* gp = (const char*)in + ((size_t)img0 * P * CIN + (size_t)i * 8) * 2;
      int lb = ((row * CIN + c8 * 8) << 1) ^ ((row & 7) << 4);
      *(short8*)(lds + lb) = *(const short8*)gp;
    }
  }
  __syncthreads();   // A visible; drains prologue B chunks 0,1 (one-time)

  f32x4 acc[M_rep][N_rep];
#pragma unroll
  for (int m = 0; m < M_rep; ++m)
#pragma unroll
    for (int n = 0; n < N_rep; ++n)
#pragma unroll
      for (int r = 0; r < 4; ++r) acc[m][n][r] = 0.f;

  int ym[M_rep], xm[M_rep], imb[M_rep];
#pragma unroll
  for (int m = 0; m < M_rep; ++m) {
    int rb2 = wm0 + m * 16;
    imb[m] = rb2 / P;
    int pp = rb2 % P + l15;
    ym[m] = pp >> LW;
    xm[m] = pp & (W - 1);
  }

  int rb = 0;
  for (int s = 0; s < NS; ++s) {
    const int tap = s / CH;
    const int dy = tap / 3, dx = tap % 3;
    if (s + 1 < NS) wait_vm<BR>(); else wait_vm<0>();
    barrier_mem();
    if (s + 2 < NS) { int sb = rb + 2; if (sb >= 3) sb -= 3; stageB(sb, s + 2); }

    int ab[M_rep]; bool av[M_rep];
#pragma unroll
    for (int m = 0; m < M_rep; ++m) {
      if constexpr (HALO) {
        ab[m] = (ym[m] + dy) * PW + xm[m] + dx;
        av[m] = true;
      } else {
        int sy = ym[m] + dy - 1, sx = xm[m] + dx - 1;
        av[m] = ((unsigned)sy < (unsigned)W) & ((unsigned)sx < (unsigned)W);
        ab[m] = imb[m] * P + sy * W + sx;
      }
    }
#pragma unroll
    for (int c2 = 0; c2 < CS / 32; ++c2) {
      const int cc = (s % CH) * (CS / 32) + c2;
      bf16x8 af[M_rep], bfr[N_rep];
#pragma unroll
      for (int m = 0; m < M_rep; ++m) {
        int lb = ((ab[m] * CIN + cc * 32 + lq * 8) << 1) ^ ((ab[m] & 7) << 4);
        if constexpr (HALO) {
          af[m] = *(const bf16x8*)(lds + lb);
        } else {
          short8 t{};
          if (av[m]) t = *(const short8*)(lds + lb);
          af[m] = __builtin_bit_cast(bf16x8, t);
        }
      }
#pragma unroll
      for (int n = 0; n < N_rep; ++n)
        bfr[n] = *(const bf16x8*)(lds + ASZ + rb * BCH +
                   (((c2 * 4 + lq) * COB + wn * WN + n * 16 + l15) << 4));
#pragma unroll
      for (int m = 0; m < M_rep; ++m)
#pragma unroll
        for (int n = 0; n < N_rep; ++n)
          acc[m][n] = __builtin_amdgcn_mfma_f32_16x16x32_bf16(af[m], bfr[n], acc[m][n], 0, 0, 0);
    }
    rb = (rb == 2) ? 0 : rb + 1;
  }

  if constexpr (STATS) {
    __syncthreads();
    float* sbuf = (float*)lds;
    for (int i = tid; i < 2 * COB; i += 512) sbuf[i] = 0.f;
    __syncthreads();
#pragma unroll
    for (int n = 0; n < N_rep; ++n) {
      float s1 = 0.f, s2 = 0.f;
#pragma unroll
      for (int m = 0; m < M_rep; ++m)
#pragma unroll
        for (int r = 0; r < 4; ++r) { float v = acc[m][n][r]; s1 += v; s2 += v * v; }
      s1 += __shfl_xor(s1, 16); s2 += __shfl_xor(s2, 16);
      s1 += __shfl_xor(s1, 32); s2 += __shfl_xor(s2, 32);
      if (lq == 0) {
        int cg = wn * WN + n * 16 + l15;
        atomicAdd(&sbuf[2 * cg], s1);
        atomicAdd(&sbuf[2 * cg + 1], s2);
      }
    }
    __syncthreads();
    for (int i = tid; i < 2 * COB; i += 512) atomicAdd(&sums[2 * co0b + i], sbuf[i]);
  }

  if constexpr (EPI == EP_RAW) {
#pragma unroll
    for (int m = 0; m < M_rep; ++m)
#pragma unroll
      for (int n = 0; n < N_rep; ++n)
#pragma unroll
        for (int r = 0; r < 4; ++r) {
          int pix = wm0 + m * 16 + lq * 4 + r;   // spans IMGS contiguous images
          bout[((size_t)img0 * P + pix) * COUT + co + n * 16 + l15] = f2bf(acc[m][n][r]);
        }
  } else if constexpr (EPI == EP_E1) {
    // fout=r1 (RMW), bout=e1b ; 8x8 result -> up2 to 16x16 ; IMGS images/block
#pragma unroll
    for (int m = 0; m < M_rep; ++m) {
      int rb2 = wm0 + m * 16;
      const int ime = img0 + rb2 / P;
      const int prow = rb2 % P;
#pragma unroll
      for (int n = 0; n < N_rep; ++n)
#pragma unroll
        for (int r = 0; r < 4; ++r) {
          int pix = prow + lq * 4 + r;
          int y = pix >> 3, x = pix & 7;
          int cg = co + n * 16 + l15;
          float t = tanhf(acc[m][n][r]);
#pragma unroll
          for (int d2 = 0; d2 < 4; ++d2) {
            size_t idx = ((size_t)ime * 256 + (2 * y + (d2 >> 1)) * 16 + 2 * x + (d2 & 1)) * 64 + cg;
            float rv = fout[idx];
            float e = rv - t;
            bout[idx] = f2bf(e);
            fout[idx] = fmaxf(rv - LRr * e, 0.f);
          }
        }
    }
  } else if constexpr (EPI == EP_E2) {
    // fout=r2 (read-only), bout=e2b ; 4x4 -> up2 to 8x8 ; IMGS images/block
#pragma unroll
    for (int m = 0; m < M_rep; ++m) {
      const int ime = img0 + imb[m];
#pragma unroll
      for (int n = 0; n < N_rep; ++n)
#pragma unroll
        for (int r = 0; r < 4; ++r) {
          int pix = lq * 4 + r;
          int y = pix >> 2, x = pix & 3;
          int cg = co + n * 16 + l15;
          float t = tanhf(acc[m][n][r]);
#pragma unroll
          for (int d2 = 0; d2 < 4; ++d2) {
            size_t idx = ((size_t)ime * 64 + (2 * y + (d2 >> 1)) * 8 + 2 * x + (d2 & 1)) * 128 + cg;
            bout[idx] = f2bf(fout[idx] - t);
          }
        }
    }
  } else if constexpr (EPI == EP_P2) {
    // fout=r2 (RMW), bout=r2b, aux=e2b ; pool 16x16 -> 8x8, in-register
#pragma unroll
    for (int m = 0; m < M_rep; m += 2)
#pragma unroll
      for (int n = 0; n < N_rep; ++n)
#pragma unroll
        for (int r0 = 0; r0 < 4; r0 += 2) {
          float sum = acc[m][n][r0] + acc[m][n][r0 + 1] + acc[m + 1][n][r0] + acc[m + 1][n][r0 + 1];
          int yo = ((wm0 >> 4) + m) >> 1;
          int xo = 2 * lq + (r0 >> 1);
          int cg = co + n * 16 + l15;
          size_t idx = ((size_t)img0 * 64 + yo * 8 + xo) * 128 + cg;
          float old = fout[idx];
          float d = 0.25f * sum - bf2f(aux[idx]);
          float nv = fmaxf(fmaf(LRr, d, old), 0.f);
          fout[idx] = nv;
          bout[idx] = f2bf(nv);
        }
  } else {
    // EP_P3: fout=r3 (RMW), bout=r3b ; pool 8x8 -> 4x4 via shfl_xor(32)
#pragma unroll
    for (int m = 0; m < M_rep; ++m) {
      int pb = wm0 + m * 16;
      int iml = pb / P;
      int yo = (pb % P) >> 4;
#pragma unroll
      for (int n = 0; n < N_rep; ++n)
#pragma unroll
        for (int r0 = 0; r0 < 4; r0 += 2) {
          float sx = acc[m][n][r0] + acc[m][n][r0 + 1];
          float sum = sx + __shfl_xor(sx, 32);
          if (l < 32) {
            int xo = 2 * (lq & 1) + (r0 >> 1);
            int cg = co + n * 16 + l15;
            size_t idx = ((size_t)(img0 + iml) * 16 + yo * 4 + xo) * COUT + cg;
            float nv = fmaxf(fmaf(LRr, 0.25f * sum, fout[idx]), 0.f);
            fout[idx] = nv;
            bout[idx] = f2bf(nv);
          }
        }
    }
  }
}

// FF layer2: conv(r1b,W2) raw + stats. 4x4 frags/wave, 90.6KB, grid 256.
__global__ __launch_bounds__(512) void ff2_k(const u16* __restrict__ in, const u16* __restrict__ wpk,
                                             u16* __restrict__ outb, float* __restrict__ sums) {
  __shared__ __align__(16) char lds[90624];
  gemm_body<16, 64, 128, 4, 2, 64, 1, 64, 1, EP_RAW, true>(
      blockIdx.x, lds, in, wpk, nullptr, outb, nullptr, sums);
}

// FF layer3: conv(r2b,W3) raw + stats. 2 imgs/block, 80KB.
__global__ __launch_bounds__(512) void ff3_k(const u16* __restrict__ in, const u16* __restrict__ wpk,
                                             u16* __restrict__ outb, float* __restrict__ sums) {
  __shared__ __align__(16) char lds[81920];
  gemm_body<8, 128, 256, 4, 2, 64, 2, 64, 2, EP_RAW, true>(
      blockIdx.x, lds, in, wpk, nullptr, outb, nullptr, sums);
}

// merged E1 (128 blocks, 2 imgs) + E2 (64 blocks, 4 imgs). 80KB.
__global__ __launch_bounds__(512) void ea_k(const u16* __restrict__ r2b, const u16* __restrict__ P2pk,
                                            float* __restrict__ r1, u16* __restrict__ e1b,
                                            const u16* __restrict__ r3b, const u16* __restrict__ P3pk,
                                            const float* __restrict__ r2, u16* __restrict__ e2b) {
  __shared__ __align__(16) char lds[81920];
  if (blockIdx.x < 128)
    gemm_body<8, 128, 64, 4, 2, 32, 1, 128, 2, EP_E1, false>(
        blockIdx.x, lds, r2b, P2pk, r1, e1b, nullptr, nullptr);
  else
    gemm_body<4, 256, 128, 2, 4, 32, 1, 64, 4, EP_E2, false>(
        blockIdx.x - 128, lds, r3b, P3pk, (float*)r2, e2b, nullptr, nullptr);
}

// P2: conv(e1b,W2) + pool + r2 update. 4x4 frags/wave, 90.6KB, grid 256.
__global__ __launch_bounds__(512) void p2_k(const u16* __restrict__ e1b, const u16* __restrict__ W2pk,
                                            float* __restrict__ r2, u16* __restrict__ r2b,
                                            const u16* __restrict__ e2b) {
  __shared__ __align__(16) char lds[90624];
  gemm_body<16, 64, 128, 4, 2, 64, 1, 64, 1, EP_P2, false>(
      blockIdx.x, lds, e1b, W2pk, r2, r2b, e2b, nullptr);
}

// P3: conv(e2b,W3) + pool + r3 update. 2 imgs/block, 80KB, grid 256.
__global__ __launch_bounds__(512) void p3_k(const u16* __restrict__ e2b, const u16* __restrict__ W3pk,
                                            float* __restrict__ r3, u16* __restrict__ r3b) {
  __shared__ __align__(16) char lds[81920];
  gemm_body<8, 128, 256, 4, 2, 64, 2, 64, 2, EP_P3, false>(
      blockIdx.x, lds, e2b, W3pk, r3, r3b, nullptr, nullptr);
}

// pack weights -> [tap][ci/8][cout][8] bf16. FLIP: conv-transpose weights.
template<int CI, int CO, bool FLIP>
__global__ __launch_bounds__(256) void pack_k(const float* __restrict__ src, u16* __restrict__ dst) {
  int idx = blockIdx.x * 256 + threadIdx.x;
  int tap = idx / (CI * CO), rem = idx % (CI * CO);
  int ci = rem / CO, c = rem % CO;
  int dy = tap / 3, dx = tap % 3;
  float v = FLIP ? src[((size_t)ci * CO + c) * 9 + (2 - dy) * 3 + (2 - dx)]
                 : src[((size_t)c * CI + ci) * 9 + dy * 3 + dx];
  dst[(((size_t)tap * (CI / 8) + (ci >> 3)) * CO + c) * 8 + (ci & 7)] = f2bf(v);
}

// pack W1 -> [k/8][64][8] with k = tap*3+cc, padded to K=32
__global__ void pack1_k(const float* __restrict__ W1, u16* __restrict__ W1pk) {
  for (int j = threadIdx.x; j < 2048; j += 256) {
    int klo = j & 7, rest = j >> 3;
    int co = rest & 63, k8 = rest >> 6;
    int k = k8 * 8 + klo;
    float v = 0.f;
    if (k < 27) {
      int tap = k / 3, cc = k % 3, dy = tap / 3, dx = tap % 3;
      v = W1[((size_t)(co * 3 + cc) * 3 + dy) * 3 + dx];
    }
    W1pk[j] = f2bf(v);
  }
}

// conv1 via MFMA (im2col K=27->32), fragments built in registers.
template<bool POOL>
__global__ __launch_bounds__(256) void c1_k(const float* __restrict__ x,
                                            const u16* __restrict__ W1pk,
                                            float* __restrict__ sums,
                                            const float* __restrict__ ss,
                                            float* __restrict__ r1,
                                            u16* __restrict__ r1b) {
  __shared__ __align__(16) char lds[28480];
  float* xs = (float*)lds;
  char* Al = lds + 3904;
  char* Bl = lds + 24384;
  const int bid = blockIdx.x;
  const int img = bid >> 2, quad = bid & 3;
  const int ty0 = (quad >> 1) * 16, tx0 = (quad & 1) * 16;
  const int tid = threadIdx.x;
  const int l = tid & 63, l15 = l & 15, lq = l >> 4;
  const int wm = tid >> 6;

  gload_lds16((const char*)W1pk + tid * 16, Bl + ((tid & 192) << 4));
  for (int i = tid; i < 972; i += 256) {
    int xx = i % 18, yy = (i / 18) % 18, cc = i / 324;
    int gy = ty0 + yy - 1, gx = tx0 + xx - 1;
    float v = 0.f;
    if (gy >= 0 && gy < 32 && gx >= 0 && gx < 32)
      v = x[((size_t)(img * 3 + cc) * 32 + gy) * 32 + gx];
    xs[i] = v;
  }
  __syncthreads();
  {
    const int ty = tid >> 4, tx = tid & 15;
#pragma unroll
    for (int i = 0; i < 4; ++i) {
      short8 v{};
#pragma unroll
      for (int j = 0; j < 8; ++j) {
        constexpr int base[4] = {0, 8, 16, 24};
        int k = base[i] + j;
        if (k < 27) {
          int tap = k / 3, cc = k % 3;
          v[j] = (short)f2bf(xs[cc * 324 + (ty + tap / 3) * 18 + tx + tap % 3]);
        }
      }
      *(short8*)(Al + tid * 80 + i * 16) = v;
    }
  }
  __syncthreads();

  f32x4 acc[4][4];
  bf16x8 af[4], bfr[4];
#pragma unroll
  for (int m = 0; m < 4; ++m) {
    int pix = wm * 64 + m * 16 + l15;
    af[m] = *(const bf16x8*)(Al + pix * 80 + lq * 16);
  }
#pragma unroll
  for (int n = 0; n < 4; ++n)
    bfr[n] = *(const bf16x8*)(Bl + ((lq * 64 + n * 16 + l15) << 4));
#pragma unroll
  for (int m = 0; m < 4; ++m)
#pragma unroll
    for (int n = 0; n < 4; ++n) {
      f32x4 z = {0.f, 0.f, 0.f, 0.f};
      acc[m][n] = __builtin_amdgcn_mfma_f32_16x16x32_bf16(af[m], bfr[n], z, 0, 0, 0);
    }

  if constexpr (!POOL) {
    float* sbuf = (float*)lds;
    __syncthreads();
    for (int i = tid; i < 128; i += 256) sbuf[i] = 0.f;
    __syncthreads();
#pragma unroll
    for (int n = 0; n < 4; ++n) {
      float s1 = 0.f, s2 = 0.f;
#pragma unroll
      for (int m = 0; m < 4; ++m)
#pragma unroll
        for (int r = 0; r < 4; ++r) { float v = acc[m][n][r]; s1 += v; s2 += v * v; }
      s1 += __shfl_xor(s1, 16); s2 += __shfl_xor(s2, 16);
      s1 += __shfl_xor(s1, 32); s2 += __shfl_xor(s2, 32);
      if (lq == 0) {
        int cg = n * 16 + l15;
        atomicAdd(&sbuf[2 * cg], s1);
        atomicAdd(&sbuf[2 * cg + 1], s2);
      }
    }
    __syncthreads();
    if (tid < 128) atomicAdd(&sums[tid], sbuf[tid]);
  } else {
    float ssv[4], ssh[4];
#pragma unroll
    for (int n = 0; n < 4; ++n) {
      ssv[n] = ss[n * 16 + l15];
      ssh[n] = ss[64 + n * 16 + l15];
    }
#pragma unroll
    for (int m = 0; m < 4; m += 2)
#pragma unroll
      for (int n = 0; n < 4; ++n)
#pragma unroll
        for (int r0 = 0; r0 < 4; r0 += 2) {
          float a0 = fmaf(acc[m][n][r0], ssv[n], ssh[n]);
          float a1 = fmaf(acc[m][n][r0 + 1], ssv[n], ssh[n]);
          float b0 = fmaf(acc[m + 1][n][r0], ssv[n], ssh[n]);
          float b1 = fmaf(acc[m + 1][n][r0 + 1], ssv[n], ssh[n]);
          float v = fmaxf(fmaxf(fmaxf(a0, a1), fmaxf(b0, b1)), 0.f);
          int py = (ty0 >> 1) + ((wm * 4 + m) >> 1);
          int px = (tx0 >> 1) + ((lq * 4 + r0) >> 1);
          size_t idx = ((size_t)img * 256 + py * 16 + px) * 64 + n * 16 + l15;
          r1[idx] = v;
          r1b[idx] = f2bf(v);
        }
  }
}

__global__ void ss_k(const float* __restrict__ sums, const float* __restrict__ g,
                     const float* __restrict__ b, float* __restrict__ ss, int C, float invN) {
  int c = blockIdx.x * 64 + threadIdx.x;
  if (c < C) {
    float m = sums[2 * c] * invN;
    float var = sums[2 * c + 1] * invN - m * m;
    float sc = g[c] * rsqrtf(var + 1e-5f);
    ss[c] = sc;
    ss[C + c] = b[c] - m * sc;
  }
}

template<int C, int H>
__global__ __launch_bounds__(256) void bnpool_k(const u16* __restrict__ t, const float* __restrict__ ss,
                                                float* __restrict__ r, u16* __restrict__ rb) {
  constexpr int HP = H / 2, C4 = C / 4;
  int idx = blockIdx.x * 256 + threadIdx.x;
  int c4 = idx % C4, po = idx / C4;
  int xo = po % HP, t2 = po / HP;
  int yo = t2 % HP, img = t2 / HP;
  const u16* p0 = t + (((size_t)img * H + 2 * yo) * H + 2 * xo) * C + c4 * 4;
  u16x4 a = *(const u16x4*)p0, b = *(const u16x4*)(p0 + C);
  u16x4 c_ = *(const u16x4*)(p0 + H * C), d = *(const u16x4*)(p0 + H * C + C);
  f32x4 sc = *(const f32x4*)(ss + c4 * 4);
  f32x4 sh = *(const f32x4*)(ss + C + c4 * 4);
  f32x4 o;
#pragma unroll
  for (int j = 0; j < 4; ++j) {
    float v0 = fmaf(bf2f(a[j]), sc[j], sh[j]);
    float v1 = fmaf(bf2f(b[j]), sc[j], sh[j]);
    float v2 = fmaf(bf2f(c_[j]), sc[j], sh[j]);
    float v3 = fmaf(bf2f(d[j]), sc[j], sh[j]);
    o[j] = fmaxf(fmaxf(fmaxf(v0, v1), fmaxf(v2, v3)), 0.f);
  }
  *(f32x4*)(r + (size_t)idx * 4) = o;
  u16x4 ob;
#pragma unroll
  for (int j = 0; j < 4; ++j) ob[j] = f2bf(o[j]);
  *(u16x4*)(rb + (size_t)idx * 4) = ob;
}

template<int P, int C, int CHUNKS>
__global__ __launch_bounds__(256) void tr_k(const float* __restrict__ in, float* __restrict__ out) {
  constexpr int TP = P / CHUNKS;
  __shared__ float tl[TP][C + 1];
  const int img = blockIdx.x, ch = blockIdx.y;
  const float* ip = in + (size_t)img * P * C;
  float* op = out + (size_t)img * P * C;
  for (int i = threadIdx.x; i < TP * C / 4; i += 256) {
    int p = i / (C / 4), c4 = i % (C / 4);
    f32x4 v = *(const f32x4*)&ip[(size_t)(ch * TP + p) * C + c4 * 4];
#pragma unroll
    for (int j = 0; j < 4; ++j) tl[p][c4 * 4 + j] = v[j];
  }
  __syncthreads();
  for (int i = threadIdx.x; i < TP * C; i += 256) {
    int c = i / TP, p = i % TP;
    op[(size_t)c * P + ch * TP + p] = tl[p][c];
  }
}

extern "C" void kernel_launch(void* const* d_in, const int* in_sizes, int n_in,
                              void* d_out, int out_size, void* d_ws, size_t ws_size,
                              hipStream_t stream) {
  const float* x  = (const float*)d_in[0];
  const float* W1 = (const float*)d_in[1];
  const float* W2 = (const float*)d_in[2];
  const float* W3 = (const float*)d_in[3];
  const float* P2 = (const float*)d_in[4];
  const float* P3 = (const float*)d_in[5];
  const float* g1 = (const float*)d_in[6];
  const float* b1 = (const float*)d_in[7];
  const float* g2 = (const float*)d_in[8];
  const float* b2 = (const float*)d_in[9];
  const float* g3 = (const float*)d_in[10];
  const float* b3 = (const float*)d_in[11];

  char* w = (char*)d_ws;
  auto alloc = [&](size_t n) { char* p = w; w += (n + 255) & ~(size_t)255; return p; };
  float* r1  = (float*)alloc(16777216);  // NHWC [256,16,16,64]
  float* r2  = (float*)alloc(8388608);   // [256,8,8,128]
  float* r3  = (float*)alloc(4194304);   // [256,4,4,256]
  u16* r1b   = (u16*)alloc(8388608);
  u16* r2b   = (u16*)alloc(4194304);
  u16* r3b   = (u16*)alloc(2097152);
  u16* W2pk  = (u16*)alloc(147456);
  u16* W3pk  = (u16*)alloc(589824);
  u16* P2pk  = (u16*)alloc(147456);
  u16* P3pk  = (u16*)alloc(589824);
  u16* W1pk  = (u16*)alloc(4096);
  float* sums = (float*)alloc(3584);
  float* ssb  = (float*)alloc(3584);
  char* S = alloc(33554432);             // t2 16MB / t3 8MB / e1b 8MB / e2b 4MB
  u16* t2 = (u16*)S;
  u16* t3 = (u16*)S;
  u16* e1b = (u16*)S;
  u16* e2b = (u16*)(S + 8388608);

  hipMemsetAsync(sums, 0, 3584, stream);

  pack_k<64, 128, false><<<288, 256, 0, stream>>>(W2, W2pk);
  pack_k<128, 256, false><<<1152, 256, 0, stream>>>(W3, W3pk);
  pack_k<128, 64, true><<<288, 256, 0, stream>>>(P2, P2pk);
  pack_k<256, 128, true><<<1152, 256, 0, stream>>>(P3, P3pk);
  pack1_k<<<1, 256, 0, stream>>>(W1, W1pk);

  // ---- feed-forward ----
  c1_k<false><<<1024, 256, 0, stream>>>(x, W1pk, sums, nullptr, nullptr, nullptr);
  ss_k<<<1, 64, 0, stream>>>(sums, g1, b1, ssb, 64, 1.f / 262144.f);
  c1_k<true><<<1024, 256, 0, stream>>>(x, W1pk, nullptr, ssb, r1, r1b);

  ff2_k<<<256, 512, 0, stream>>>(r1b, W2pk, t2, sums + 128);
  ss_k<<<2, 64, 0, stream>>>(sums + 128, g2, b2, ssb + 128, 128, 1.f / 65536.f);
  bnpool_k<128, 16><<<2048, 256, 0, stream>>>(t2, ssb + 128, r2, r2b);

  ff3_k<<<256, 512, 0, stream>>>(r2b, W3pk, t3, sums + 384);
  ss_k<<<4, 64, 0, stream>>>(sums + 384, g3, b3, ssb + 384, 256, 1.f / 16384.f);
  bnpool_k<256, 8><<<1024, 256, 0, stream>>>(t3, ssb + 384, r3, r3b);

  // ---- predictive-coding iterations (3 dispatches / iter) ----
  for (int it = 0; it < 10; ++it) {
    ea_k<<<192, 512, 0, stream>>>(r2b, P2pk, r1, e1b, r3b, P3pk, r2, e2b);
    p2_k<<<256, 512, 0, stream>>>(e1b, W2pk, r2, r2b, e2b);
    p3_k<<<256, 512, 0, stream>>>(e2b, W3pk, r3, r3b);
  }

  // ---- NHWC -> NCHW outputs ----
  float* out = (float*)d_out;
  tr_k<256, 64, 4><<<dim3(256, 4), 256, 0, stream>>>(r1, out);
  tr_k<64, 128, 1><<<dim3(256, 1), 256, 0, stream>>>(r2, out + 4194304);
  tr_k<16, 256, 1><<<dim3(256, 1), 256, 0, stream>>>(r3, out + 6291456);
}

// Round 14
// 698.307 us; speedup vs baseline: 1.0617x; 1.0617x over previous
//
#include <hip/hip_runtime.h>
#include <cstddef>
#include <cstdint>

#define LRr 0.02f

typedef unsigned short u16;
typedef __attribute__((ext_vector_type(8))) __bf16 bf16x8;
typedef __attribute__((ext_vector_type(8))) short short8;
typedef __attribute__((ext_vector_type(4))) float f32x4;
typedef __attribute__((ext_vector_type(4))) u16 u16x4;

static __device__ __forceinline__ u16 f2bf(float f) {
  union { float f; unsigned int u; } v{f};
  unsigned int r = (v.u + 0x7FFFu + ((v.u >> 16) & 1u)) >> 16;
  return (u16)r;
}
static __device__ __forceinline__ float bf2f(u16 h) {
  union { unsigned int u; float f; } v{(unsigned int)h << 16};
  return v.f;
}

static __device__ __forceinline__ void gload_lds16(const void* g, void* l) {
  __builtin_amdgcn_global_load_lds(
      (const __attribute__((address_space(1))) unsigned int*)g,
      (__attribute__((address_space(3))) unsigned int*)l, 16, 0, 0);
}

// counted waitcnt: allow N outstanding VMEM ops
template<int N> static __device__ __forceinline__ void wait_vm() {
  if constexpr (N <= 0)      asm volatile("s_waitcnt vmcnt(0)" ::: "memory");
  else if constexpr (N == 1) asm volatile("s_waitcnt vmcnt(1)" ::: "memory");
  else if constexpr (N == 2) asm volatile("s_waitcnt vmcnt(2)" ::: "memory");
  else if constexpr (N == 3) asm volatile("s_waitcnt vmcnt(3)" ::: "memory");
  else if constexpr (N == 4) asm volatile("s_waitcnt vmcnt(4)" ::: "memory");
  else                       asm volatile("s_waitcnt vmcnt(6)" ::: "memory");
}
static __device__ __forceinline__ void barrier_mem() {
  asm volatile("s_barrier" ::: "memory");
}

enum { EP_RAW = 0, EP_E1 = 1, EP_E2 = 2, EP_P2 = 3, EP_P3 = 4 };

// Implicit-GEMM 3x3 conv, pad=1, NHWC bf16 — 512-thread / 8-wave blocks
// (r12-winning config). B triple-buffered per CS-chunk via global_load_lds +
// counted vmcnt(BR) + raw s_barrier. r14: p2+p3 merged into one 768-block
// dispatch so p3's work backfills CUs as p2 blocks retire (r12 ran p3 on
// half the machine).
template<int H, int CIN, int COUT, int WAVES_M, int WAVES_N, int WN, int NBLK,
         int CS, int IMGS, int EPI, bool STATS>
__device__ __forceinline__ void gemm_body(
    int bid, char* lds,
    const u16* __restrict__ in, const u16* __restrict__ wpk,
    float* __restrict__ fout, u16* __restrict__ bout,
    const u16* __restrict__ aux, float* __restrict__ sums)
{
  constexpr int P = H * H, W = H;
  constexpr int LW = (H == 16) ? 4 : ((H == 8) ? 3 : 2);
  constexpr bool HALO = (IMGS == 1);
  constexpr int MROWS = IMGS * P;
  constexpr int WM = MROWS / WAVES_M;
  constexpr int M_rep = WM / 16, N_rep = WN / 16;
  constexpr int COB = WAVES_N * WN;
  constexpr int PW = H + 2;
  constexpr int ASZ = HALO ? PW * PW * CIN * 2 : MROWS * CIN * 2;
  constexpr int BCH = CS * COB * 2;
  constexpr int CH = CIN / CS;
  constexpr int NS = 9 * CH;
  constexpr int BR = (CS * COB) / 4096;
  static_assert(COB * NBLK == COUT, "n");
  static_assert(WAVES_M * WAVES_N == 8, "w");
  static_assert(ASZ + 3 * BCH <= 163840 / 2, "lds");
  static_assert((CS * COB) % 4096 == 0, "br");

  const int tid = threadIdx.x;
  const int l = tid & 63, l15 = l & 15, lq = l >> 4;
  const int wid = tid >> 6;
  const int wn = wid % WAVES_N, wm = wid / WAVES_N;
  const int img0 = (bid / NBLK) * IMGS;
  const int half = bid % NBLK;
  const int co0b = half * COB;
  const int wm0 = wm * WM;
  const int co = co0b + wn * WN;

  auto stageB = [&](int buf, int s) {
    int tap = s / CH, ch = s % CH;
#pragma unroll
    for (int r = 0; r < BR; ++r) {
      int j = r * 512 + tid;
      int ci8 = ch * (CS / 8) + j / COB, c = j % COB;
      const char* gp = (const char*)wpk +
          ((size_t)((tap * (CIN / 8) + ci8) * COUT + co0b + c) << 4);
      char* lp = lds + ASZ + buf * BCH + ((r * 512 + (tid & 448)) << 4);
      gload_lds16(gp, lp);
    }
  };

  stageB(0, 0);
  stageB(1, 1);

  if constexpr (HALO) {
    for (int i = tid * 16; i < ASZ; i += 8192)
      *(int4*)(lds + i) = make_int4(0, 0, 0, 0);
    __syncthreads();
    constexpr int NCH = P * CIN / 8;
    for (int i = tid; i < NCH; i += 512) {
      int pix = i / (CIN / 8), c8 = i % (CIN / 8);
      const char* gp = (const char*)in + (((size_t)img0 * P + pix) * CIN + c8 * 8) * 2;
      int cell = ((pix >> LW) + 1) * PW + (pix & (W - 1)) + 1;
      int lb = ((cell * CIN + c8 * 8) << 1) ^ ((cell & 7) << 4);
      *(short8*)(lds + lb) = *(const short8*)gp;
    }
  } else {
    constexpr int NCH = MROWS * CIN / 8;
    for (int i = tid; i < NCH; i += 512) {
      int row = i / (CIN / 8), c8 = i % (CIN / 8);
      const char* gp = (const char*)in + ((size_t)img0 * P * CIN + (size_t)i * 8) * 2;
      int lb = ((row * CIN + c8 * 8) << 1) ^ ((row & 7) << 4);
      *(short8*)(lds + lb) = *(const short8*)gp;
    }
  }
  __syncthreads();   // A visible; drains prologue B chunks 0,1 (one-time)

  f32x4 acc[M_rep][N_rep];
#pragma unroll
  for (int m = 0; m < M_rep; ++m)
#pragma unroll
    for (int n = 0; n < N_rep; ++n)
#pragma unroll
      for (int r = 0; r < 4; ++r) acc[m][n][r] = 0.f;

  int ym[M_rep], xm[M_rep], imb[M_rep];
#pragma unroll
  for (int m = 0; m < M_rep; ++m) {
    int rb2 = wm0 + m * 16;
    imb[m] = rb2 / P;
    int pp = rb2 % P + l15;
    ym[m] = pp >> LW;
    xm[m] = pp & (W - 1);
  }

  int rb = 0;
  for (int s = 0; s < NS; ++s) {
    const int tap = s / CH;
    const int dy = tap / 3, dx = tap % 3;
    if (s + 1 < NS) wait_vm<BR>(); else wait_vm<0>();
    barrier_mem();
    if (s + 2 < NS) { int sb = rb + 2; if (sb >= 3) sb -= 3; stageB(sb, s + 2); }

    int ab[M_rep]; bool av[M_rep];
#pragma unroll
    for (int m = 0; m < M_rep; ++m) {
      if constexpr (HALO) {
        ab[m] = (ym[m] + dy) * PW + xm[m] + dx;
        av[m] = true;
      } else {
        int sy = ym[m] + dy - 1, sx = xm[m] + dx - 1;
        av[m] = ((unsigned)sy < (unsigned)W) & ((unsigned)sx < (unsigned)W);
        ab[m] = imb[m] * P + sy * W + sx;
      }
    }
#pragma unroll
    for (int c2 = 0; c2 < CS / 32; ++c2) {
      const int cc = (s % CH) * (CS / 32) + c2;
      bf16x8 af[M_rep], bfr[N_rep];
#pragma unroll
      for (int m = 0; m < M_rep; ++m) {
        int lb = ((ab[m] * CIN + cc * 32 + lq * 8) << 1) ^ ((ab[m] & 7) << 4);
        if constexpr (HALO) {
          af[m] = *(const bf16x8*)(lds + lb);
        } else {
          short8 t{};
          if (av[m]) t = *(const short8*)(lds + lb);
          af[m] = __builtin_bit_cast(bf16x8, t);
        }
      }
#pragma unroll
      for (int n = 0; n < N_rep; ++n)
        bfr[n] = *(const bf16x8*)(lds + ASZ + rb * BCH +
                   (((c2 * 4 + lq) * COB + wn * WN + n * 16 + l15) << 4));
#pragma unroll
      for (int m = 0; m < M_rep; ++m)
#pragma unroll
        for (int n = 0; n < N_rep; ++n)
          acc[m][n] = __builtin_amdgcn_mfma_f32_16x16x32_bf16(af[m], bfr[n], acc[m][n], 0, 0, 0);
    }
    rb = (rb == 2) ? 0 : rb + 1;
  }

  if constexpr (STATS) {
    __syncthreads();
    float* sbuf = (float*)lds;
    for (int i = tid; i < 2 * COB; i += 512) sbuf[i] = 0.f;
    __syncthreads();
#pragma unroll
    for (int n = 0; n < N_rep; ++n) {
      float s1 = 0.f, s2 = 0.f;
#pragma unroll
      for (int m = 0; m < M_rep; ++m)
#pragma unroll
        for (int r = 0; r < 4; ++r) { float v = acc[m][n][r]; s1 += v; s2 += v * v; }
      s1 += __shfl_xor(s1, 16); s2 += __shfl_xor(s2, 16);
      s1 += __shfl_xor(s1, 32); s2 += __shfl_xor(s2, 32);
      if (lq == 0) {
        int cg = wn * WN + n * 16 + l15;
        atomicAdd(&sbuf[2 * cg], s1);
        atomicAdd(&sbuf[2 * cg + 1], s2);
      }
    }
    __syncthreads();
    for (int i = tid; i < 2 * COB; i += 512) atomicAdd(&sums[2 * co0b + i], sbuf[i]);
  }

  if constexpr (EPI == EP_RAW) {
#pragma unroll
    for (int m = 0; m < M_rep; ++m)
#pragma unroll
      for (int n = 0; n < N_rep; ++n)
#pragma unroll
        for (int r = 0; r < 4; ++r) {
          int pix = wm0 + m * 16 + lq * 4 + r;   // spans IMGS contiguous images
          bout[((size_t)img0 * P + pix) * COUT + co + n * 16 + l15] = f2bf(acc[m][n][r]);
        }
  } else if constexpr (EPI == EP_E1) {
    // fout=r1 (RMW), bout=e1b ; 8x8 result -> up2 to 16x16 ; IMGS images/block
#pragma unroll
    for (int m = 0; m < M_rep; ++m) {
      int rb2 = wm0 + m * 16;
      const int ime = img0 + rb2 / P;
      const int prow = rb2 % P;
#pragma unroll
      for (int n = 0; n < N_rep; ++n)
#pragma unroll
        for (int r = 0; r < 4; ++r) {
          int pix = prow + lq * 4 + r;
          int y = pix >> 3, x = pix & 7;
          int cg = co + n * 16 + l15;
          float t = tanhf(acc[m][n][r]);
#pragma unroll
          for (int d2 = 0; d2 < 4; ++d2) {
            size_t idx = ((size_t)ime * 256 + (2 * y + (d2 >> 1)) * 16 + 2 * x + (d2 & 1)) * 64 + cg;
            float rv = fout[idx];
            float e = rv - t;
            bout[idx] = f2bf(e);
            fout[idx] = fmaxf(rv - LRr * e, 0.f);
          }
        }
    }
  } else if constexpr (EPI == EP_E2) {
    // fout=r2 (read-only), bout=e2b ; 4x4 -> up2 to 8x8 ; IMGS images/block
#pragma unroll
    for (int m = 0; m < M_rep; ++m) {
      const int ime = img0 + imb[m];
#pragma unroll
      for (int n = 0; n < N_rep; ++n)
#pragma unroll
        for (int r = 0; r < 4; ++r) {
          int pix = lq * 4 + r;
          int y = pix >> 2, x = pix & 3;
          int cg = co + n * 16 + l15;
          float t = tanhf(acc[m][n][r]);
#pragma unroll
          for (int d2 = 0; d2 < 4; ++d2) {
            size_t idx = ((size_t)ime * 64 + (2 * y + (d2 >> 1)) * 8 + 2 * x + (d2 & 1)) * 128 + cg;
            bout[idx] = f2bf(fout[idx] - t);
          }
        }
    }
  } else if constexpr (EPI == EP_P2) {
    // fout=r2 (RMW), bout=r2b, aux=e2b ; pool 16x16 -> 8x8, in-register
#pragma unroll
    for (int m = 0; m < M_rep; m += 2)
#pragma unroll
      for (int n = 0; n < N_rep; ++n)
#pragma unroll
        for (int r0 = 0; r0 < 4; r0 += 2) {
          float sum = acc[m][n][r0] + acc[m][n][r0 + 1] + acc[m + 1][n][r0] + acc[m + 1][n][r0 + 1];
          int yo = ((wm0 >> 4) + m) >> 1;
          int xo = 2 * lq + (r0 >> 1);
          int cg = co + n * 16 + l15;
          size_t idx = ((size_t)img0 * 64 + yo * 8 + xo) * 128 + cg;
          float old = fout[idx];
          float d = 0.25f * sum - bf2f(aux[idx]);
          float nv = fmaxf(fmaf(LRr, d, old), 0.f);
          fout[idx] = nv;
          bout[idx] = f2bf(nv);
        }
  } else {
    // EP_P3: fout=r3 (RMW), bout=r3b ; pool 8x8 -> 4x4 via shfl_xor(32)
#pragma unroll
    for (int m = 0; m < M_rep; ++m) {
      int pb = wm0 + m * 16;
      int iml = pb / P;
      int yo = (pb % P) >> 4;
#pragma unroll
      for (int n = 0; n < N_rep; ++n)
#pragma unroll
        for (int r0 = 0; r0 < 4; r0 += 2) {
          float sx = acc[m][n][r0] + acc[m][n][r0 + 1];
          float sum = sx + __shfl_xor(sx, 32);
          if (l < 32) {
            int xo = 2 * (lq & 1) + (r0 >> 1);
            int cg = co + n * 16 + l15;
            size_t idx = ((size_t)(img0 + iml) * 16 + yo * 4 + xo) * COUT + cg;
            float nv = fmaxf(fmaf(LRr, 0.25f * sum, fout[idx]), 0.f);
            fout[idx] = nv;
            bout[idx] = f2bf(nv);
          }
        }
    }
  }
}

// FF layer2: conv(r1b,W2) raw + stats. 66KB LDS, grid 512 (r12 shape).
__global__ __launch_bounds__(512) void ff2_k(const u16* __restrict__ in, const u16* __restrict__ wpk,
                                             u16* __restrict__ outb, float* __restrict__ sums) {
  __shared__ __align__(16) char lds[66048];
  gemm_body<16, 64, 128, 4, 2, 32, 2, 64, 1, EP_RAW, true>(
      blockIdx.x, lds, in, wpk, nullptr, outb, nullptr, sums);
}

// FF layer3: conv(r2b,W3) raw + stats. 2 imgs/block, 80KB, grid 256.
__global__ __launch_bounds__(512) void ff3_k(const u16* __restrict__ in, const u16* __restrict__ wpk,
                                             u16* __restrict__ outb, float* __restrict__ sums) {
  __shared__ __align__(16) char lds[81920];
  gemm_body<8, 128, 256, 4, 2, 64, 2, 64, 2, EP_RAW, true>(
      blockIdx.x, lds, in, wpk, nullptr, outb, nullptr, sums);
}

// merged E1 (128 blocks, 2 imgs) + E2 (64 blocks, 4 imgs). 80KB, grid 192.
__global__ __launch_bounds__(512) void ea_k(const u16* __restrict__ r2b, const u16* __restrict__ P2pk,
                                            float* __restrict__ r1, u16* __restrict__ e1b,
                                            const u16* __restrict__ r3b, const u16* __restrict__ P3pk,
                                            const float* __restrict__ r2, u16* __restrict__ e2b) {
  __shared__ __align__(16) char lds[81920];
  if (blockIdx.x < 128)
    gemm_body<8, 128, 64, 4, 2, 32, 1, 128, 2, EP_E1, false>(
        blockIdx.x, lds, r2b, P2pk, r1, e1b, nullptr, nullptr);
  else
    gemm_body<4, 256, 128, 2, 4, 32, 1, 64, 4, EP_E2, false>(
        blockIdx.x - 128, lds, r3b, P3pk, (float*)r2, e2b, nullptr, nullptr);
}

// merged P2 (512 blocks) + P3 (256 blocks, 2 imgs). 80KB, grid 768:
// p3 work backfills CUs as p2 blocks retire.
__global__ __launch_bounds__(512) void pb_k(const u16* __restrict__ e1b, const u16* __restrict__ W2pk,
                                            float* __restrict__ r2, u16* __restrict__ r2b,
                                            const u16* __restrict__ e2b, const u16* __restrict__ W3pk,
                                            float* __restrict__ r3, u16* __restrict__ r3b) {
  __shared__ __align__(16) char lds[81920];
  if (blockIdx.x < 512)
    gemm_body<16, 64, 128, 4, 2, 32, 2, 64, 1, EP_P2, false>(
        blockIdx.x, lds, e1b, W2pk, r2, r2b, e2b, nullptr);
  else
    gemm_body<8, 128, 256, 4, 2, 64, 2, 64, 2, EP_P3, false>(
        blockIdx.x - 512, lds, e2b, W3pk, r3, r3b, nullptr, nullptr);
}

// pack weights -> [tap][ci/8][cout][8] bf16. FLIP: conv-transpose weights.
template<int CI, int CO, bool FLIP>
__global__ __launch_bounds__(256) void pack_k(const float* __restrict__ src, u16* __restrict__ dst) {
  int idx = blockIdx.x * 256 + threadIdx.x;
  int tap = idx / (CI * CO), rem = idx % (CI * CO);
  int ci = rem / CO, c = rem % CO;
  int dy = tap / 3, dx = tap % 3;
  float v = FLIP ? src[((size_t)ci * CO + c) * 9 + (2 - dy) * 3 + (2 - dx)]
                 : src[((size_t)c * CI + ci) * 9 + dy * 3 + dx];
  dst[(((size_t)tap * (CI / 8) + (ci >> 3)) * CO + c) * 8 + (ci & 7)] = f2bf(v);
}

// pack W1 -> [k/8][64][8] with k = tap*3+cc, padded to K=32
__global__ void pack1_k(const float* __restrict__ W1, u16* __restrict__ W1pk) {
  for (int j = threadIdx.x; j < 2048; j += 256) {
    int klo = j & 7, rest = j >> 3;
    int co = rest & 63, k8 = rest >> 6;
    int k = k8 * 8 + klo;
    float v = 0.f;
    if (k < 27) {
      int tap = k / 3, cc = k % 3, dy = tap / 3, dx = tap % 3;
      v = W1[((size_t)(co * 3 + cc) * 3 + dy) * 3 + dx];
    }
    W1pk[j] = f2bf(v);
  }
}

// conv1 via MFMA (im2col K=27->32), fragments built in registers.
template<bool POOL>
__global__ __launch_bounds__(256) void c1_k(const float* __restrict__ x,
                                            const u16* __restrict__ W1pk,
                                            float* __restrict__ sums,
                                            const float* __restrict__ ss,
                                            float* __restrict__ r1,
                                            u16* __restrict__ r1b) {
  __shared__ __align__(16) char lds[28480];
  float* xs = (float*)lds;
  char* Al = lds + 3904;
  char* Bl = lds + 24384;
  const int bid = blockIdx.x;
  const int img = bid >> 2, quad = bid & 3;
  const int ty0 = (quad >> 1) * 16, tx0 = (quad & 1) * 16;
  const int tid = threadIdx.x;
  const int l = tid & 63, l15 = l & 15, lq = l >> 4;
  const int wm = tid >> 6;

  gload_lds16((const char*)W1pk + tid * 16, Bl + ((tid & 192) << 4));
  for (int i = tid; i < 972; i += 256) {
    int xx = i % 18, yy = (i / 18) % 18, cc = i / 324;
    int gy = ty0 + yy - 1, gx = tx0 + xx - 1;
    float v = 0.f;
    if (gy >= 0 && gy < 32 && gx >= 0 && gx < 32)
      v = x[((size_t)(img * 3 + cc) * 32 + gy) * 32 + gx];
    xs[i] = v;
  }
  __syncthreads();
  {
    const int ty = tid >> 4, tx = tid & 15;
#pragma unroll
    for (int i = 0; i < 4; ++i) {
      short8 v{};
#pragma unroll
      for (int j = 0; j < 8; ++j) {
        constexpr int base[4] = {0, 8, 16, 24};
        int k = base[i] + j;
        if (k < 27) {
          int tap = k / 3, cc = k % 3;
          v[j] = (short)f2bf(xs[cc * 324 + (ty + tap / 3) * 18 + tx + tap % 3]);
        }
      }
      *(short8*)(Al + tid * 80 + i * 16) = v;
    }
  }
  __syncthreads();

  f32x4 acc[4][4];
  bf16x8 af[4], bfr[4];
#pragma unroll
  for (int m = 0; m < 4; ++m) {
    int pix = wm * 64 + m * 16 + l15;
    af[m] = *(const bf16x8*)(Al + pix * 80 + lq * 16);
  }
#pragma unroll
  for (int n = 0; n < 4; ++n)
    bfr[n] = *(const bf16x8*)(Bl + ((lq * 64 + n * 16 + l15) << 4));
#pragma unroll
  for (int m = 0; m < 4; ++m)
#pragma unroll
    for (int n = 0; n < 4; ++n) {
      f32x4 z = {0.f, 0.f, 0.f, 0.f};
      acc[m][n] = __builtin_amdgcn_mfma_f32_16x16x32_bf16(af[m], bfr[n], z, 0, 0, 0);
    }

  if constexpr (!POOL) {
    float* sbuf = (float*)lds;
    __syncthreads();
    for (int i = tid; i < 128; i += 256) sbuf[i] = 0.f;
    __syncthreads();
#pragma unroll
    for (int n = 0; n < 4; ++n) {
      float s1 = 0.f, s2 = 0.f;
#pragma unroll
      for (int m = 0; m < 4; ++m)
#pragma unroll
        for (int r = 0; r < 4; ++r) { float v = acc[m][n][r]; s1 += v; s2 += v * v; }
      s1 += __shfl_xor(s1, 16); s2 += __shfl_xor(s2, 16);
      s1 += __shfl_xor(s1, 32); s2 += __shfl_xor(s2, 32);
      if (lq == 0) {
        int cg = n * 16 + l15;
        atomicAdd(&sbuf[2 * cg], s1);
        atomicAdd(&sbuf[2 * cg + 1], s2);
      }
    }
    __syncthreads();
    if (tid < 128) atomicAdd(&sums[tid], sbuf[tid]);
  } else {
    float ssv[4], ssh[4];
#pragma unroll
    for (int n = 0; n < 4; ++n) {
      ssv[n] = ss[n * 16 + l15];
      ssh[n] = ss[64 + n * 16 + l15];
    }
#pragma unroll
    for (int m = 0; m < 4; m += 2)
#pragma unroll
      for (int n = 0; n < 4; ++n)
#pragma unroll
        for (int r0 = 0; r0 < 4; r0 += 2) {
          float a0 = fmaf(acc[m][n][r0], ssv[n], ssh[n]);
          float a1 = fmaf(acc[m][n][r0 + 1], ssv[n], ssh[n]);
          float b0 = fmaf(acc[m + 1][n][r0], ssv[n], ssh[n]);
          float b1 = fmaf(acc[m + 1][n][r0 + 1], ssv[n], ssh[n]);
          float v = fmaxf(fmaxf(fmaxf(a0, a1), fmaxf(b0, b1)), 0.f);
          int py = (ty0 >> 1) + ((wm * 4 + m) >> 1);
          int px = (tx0 >> 1) + ((lq * 4 + r0) >> 1);
          size_t idx = ((size_t)img * 256 + py * 16 + px) * 64 + n * 16 + l15;
          r1[idx] = v;
          r1b[idx] = f2bf(v);
        }
  }
}

__global__ void ss_k(const float* __restrict__ sums, const float* __restrict__ g,
                     const float* __restrict__ b, float* __restrict__ ss, int C, float invN) {
  int c = blockIdx.x * 64 + threadIdx.x;
  if (c < C) {
    float m = sums[2 * c] * invN;
    float var = sums[2 * c + 1] * invN - m * m;
    float sc = g[c] * rsqrtf(var + 1e-5f);
    ss[c] = sc;
    ss[C + c] = b[c] - m * sc;
  }
}

template<int C, int H>
__global__ __launch_bounds__(256) void bnpool_k(const u16* __restrict__ t, const float* __restrict__ ss,
                                                float* __restrict__ r, u16* __restrict__ rb) {
  constexpr int HP = H / 2, C4 = C / 4;
  int idx = blockIdx.x * 256 + threadIdx.x;
  int c4 = idx % C4, po = idx / C4;
  int xo = po % HP, t2 = po / HP;
  int yo = t2 % HP, img = t2 / HP;
  const u16* p0 = t + (((size_t)img * H + 2 * yo) * H + 2 * xo) * C + c4 * 4;
  u16x4 a = *(const u16x4*)p0, b = *(const u16x4*)(p0 + C);
  u16x4 c_ = *(const u16x4*)(p0 + H * C), d = *(const u16x4*)(p0 + H * C + C);
  f32x4 sc = *(const f32x4*)(ss + c4 * 4);
  f32x4 sh = *(const f32x4*)(ss + C + c4 * 4);
  f32x4 o;
#pragma unroll
  for (int j = 0; j < 4; ++j) {
    float v0 = fmaf(bf2f(a[j]), sc[j], sh[j]);
    float v1 = fmaf(bf2f(b[j]), sc[j], sh[j]);
    float v2 = fmaf(bf2f(c_[j]), sc[j], sh[j]);
    float v3 = fmaf(bf2f(d[j]), sc[j], sh[j]);
    o[j] = fmaxf(fmaxf(fmaxf(v0, v1), fmaxf(v2, v3)), 0.f);
  }
  *(f32x4*)(r + (size_t)idx * 4) = o;
  u16x4 ob;
#pragma unroll
  for (int j = 0; j < 4; ++j) ob[j] = f2bf(o[j]);
  *(u16x4*)(rb + (size_t)idx * 4) = ob;
}

template<int P, int C, int CHUNKS>
__global__ __launch_bounds__(256) void tr_k(const float* __restrict__ in, float* __restrict__ out) {
  constexpr int TP = P / CHUNKS;
  __shared__ float tl[TP][C + 1];
  const int img = blockIdx.x, ch = blockIdx.y;
  const float* ip = in + (size_t)img * P * C;
  float* op = out + (size_t)img * P * C;
  for (int i = threadIdx.x; i < TP * C / 4; i += 256) {
    int p = i / (C / 4), c4 = i % (C / 4);
    f32x4 v = *(const f32x4*)&ip[(size_t)(ch * TP + p) * C + c4 * 4];
#pragma unroll
    for (int j = 0; j < 4; ++j) tl[p][c4 * 4 + j] = v[j];
  }
  __syncthreads();
  for (int i = threadIdx.x; i < TP * C; i += 256) {
    int c = i / TP, p = i % TP;
    op[(size_t)c * P + ch * TP + p] = tl[p][c];
  }
}

extern "C" void kernel_launch(void* const* d_in, const int* in_sizes, int n_in,
                              void* d_out, int out_size, void* d_ws, size_t ws_size,
                              hipStream_t stream) {
  const float* x  = (const float*)d_in[0];
  const float* W1 = (const float*)d_in[1];
  const float* W2 = (const float*)d_in[2];
  const float* W3 = (const float*)d_in[3];
  const float* P2 = (const float*)d_in[4];
  const float* P3 = (const float*)d_in[5];
  const float* g1 = (const float*)d_in[6];
  const float* b1 = (const float*)d_in[7];
  const float* g2 = (const float*)d_in[8];
  const float* b2 = (const float*)d_in[9];
  const float* g3 = (const float*)d_in[10];
  const float* b3 = (const float*)d_in[11];

  char* w = (char*)d_ws;
  auto alloc = [&](size_t n) { char* p = w; w += (n + 255) & ~(size_t)255; return p; };
  float* r1  = (float*)alloc(16777216);  // NHWC [256,16,16,64]
  float* r2  = (float*)alloc(8388608);   // [256,8,8,128]
  float* r3  = (float*)alloc(4194304);   // [256,4,4,256]
  u16* r1b   = (u16*)alloc(8388608);
  u16* r2b   = (u16*)alloc(4194304);
  u16* r3b   = (u16*)alloc(2097152);
  u16* W2pk  = (u16*)alloc(147456);
  u16* W3pk  = (u16*)alloc(589824);
  u16* P2pk  = (u16*)alloc(147456);
  u16* P3pk  = (u16*)alloc(589824);
  u16* W1pk  = (u16*)alloc(4096);
  float* sums = (float*)alloc(3584);
  float* ssb  = (float*)alloc(3584);
  char* S = alloc(33554432);             // t2 16MB / t3 8MB / e1b 8MB / e2b 4MB
  u16* t2 = (u16*)S;
  u16* t3 = (u16*)S;
  u16* e1b = (u16*)S;
  u16* e2b = (u16*)(S + 8388608);

  hipMemsetAsync(sums, 0, 3584, stream);

  pack_k<64, 128, false><<<288, 256, 0, stream>>>(W2, W2pk);
  pack_k<128, 256, false><<<1152, 256, 0, stream>>>(W3, W3pk);
  pack_k<128, 64, true><<<288, 256, 0, stream>>>(P2, P2pk);
  pack_k<256, 128, true><<<1152, 256, 0, stream>>>(P3, P3pk);
  pack1_k<<<1, 256, 0, stream>>>(W1, W1pk);

  // ---- feed-forward ----
  c1_k<false><<<1024, 256, 0, stream>>>(x, W1pk, sums, nullptr, nullptr, nullptr);
  ss_k<<<1, 64, 0, stream>>>(sums, g1, b1, ssb, 64, 1.f / 262144.f);
  c1_k<true><<<1024, 256, 0, stream>>>(x, W1pk, nullptr, ssb, r1, r1b);

  ff2_k<<<512, 512, 0, stream>>>(r1b, W2pk, t2, sums + 128);
  ss_k<<<2, 64, 0, stream>>>(sums + 128, g2, b2, ssb + 128, 128, 1.f / 65536.f);
  bnpool_k<128, 16><<<2048, 256, 0, stream>>>(t2, ssb + 128, r2, r2b);

  ff3_k<<<256, 512, 0, stream>>>(r2b, W3pk, t3, sums + 384);
  ss_k<<<4, 64, 0, stream>>>(sums + 384, g3, b3, ssb + 384, 256, 1.f / 16384.f);
  bnpool_k<256, 8><<<1024, 256, 0, stream>>>(t3, ssb + 384, r3, r3b);

  // ---- predictive-coding iterations (2 dispatches / iter) ----
  for (int it = 0; it < 10; ++it) {
    ea_k<<<192, 512, 0, stream>>>(r2b, P2pk, r1, e1b, r3b, P3pk, r2, e2b);
    pb_k<<<768, 512, 0, stream>>>(e1b, W2pk, r2, r2b, e2b, W3pk, r3, r3b);
  }

  // ---- NHWC -> NCHW outputs ----
  float* out = (float*)d_out;
  tr_k<256, 64, 4><<<dim3(256, 4), 256, 0, stream>>>(r1, out);
  tr_k<64, 128, 1><<<dim3(256, 1), 256, 0, stream>>>(r2, out + 4194304);
  tr_k<16, 256, 1><<<dim3(256, 1), 256, 0, stream>>>(r3, out + 6291456);
}

// Round 15
// 663.660 us; speedup vs baseline: 1.1172x; 1.0522x over previous
//
#include <hip/hip_runtime.h>
#include <cstddef>
#include <cstdint>

#define LRr 0.02f

typedef unsigned short u16;
typedef __attribute__((ext_vector_type(8))) __bf16 bf16x8;
typedef __attribute__((ext_vector_type(8))) short short8;
typedef __attribute__((ext_vector_type(4))) float f32x4;
typedef __attribute__((ext_vector_type(4))) u16 u16x4;

static __device__ __forceinline__ u16 f2bf(float f) {
  union { float f; unsigned int u; } v{f};
  unsigned int r = (v.u + 0x7FFFu + ((v.u >> 16) & 1u)) >> 16;
  return (u16)r;
}
static __device__ __forceinline__ float bf2f(u16 h) {
  union { unsigned int u; float f; } v{(unsigned int)h << 16};
  return v.f;
}

static __device__ __forceinline__ void gload_lds16(const void* g, void* l) {
  __builtin_amdgcn_global_load_lds(
      (const __attribute__((address_space(1))) unsigned int*)g,
      (__attribute__((address_space(3))) unsigned int*)l, 16, 0, 0);
}

// counted waitcnt: allow N outstanding VMEM ops
template<int N> static __device__ __forceinline__ void wait_vm() {
  if constexpr (N <= 0)      asm volatile("s_waitcnt vmcnt(0)" ::: "memory");
  else if constexpr (N == 1) asm volatile("s_waitcnt vmcnt(1)" ::: "memory");
  else if constexpr (N == 2) asm volatile("s_waitcnt vmcnt(2)" ::: "memory");
  else if constexpr (N == 3) asm volatile("s_waitcnt vmcnt(3)" ::: "memory");
  else if constexpr (N == 4) asm volatile("s_waitcnt vmcnt(4)" ::: "memory");
  else                       asm volatile("s_waitcnt vmcnt(6)" ::: "memory");
}
static __device__ __forceinline__ void barrier_mem() {
  asm volatile("s_barrier" ::: "memory");
}

enum { EP_RAW = 0, EP_E1 = 1, EP_E2 = 2, EP_P2 = 3, EP_P3 = 4 };

// Implicit-GEMM 3x3 conv, pad=1, NHWC bf16 — 512-thread / 8-wave blocks.
// B triple-buffered per CS-chunk via global_load_lds + counted vmcnt(BR) +
// raw s_barrier. r15: (a) E1 back to 1 img/block -> ea grid 320 (full CU
// fill vs 192); (b) s_setprio(1) around the MFMA cluster (T5 — chunk loop
// has wave role diversity under counted vmcnt).
template<int H, int CIN, int COUT, int WAVES_M, int WAVES_N, int WN, int NBLK,
         int CS, int IMGS, int EPI, bool STATS>
__device__ __forceinline__ void gemm_body(
    int bid, char* lds,
    const u16* __restrict__ in, const u16* __restrict__ wpk,
    float* __restrict__ fout, u16* __restrict__ bout,
    const u16* __restrict__ aux, float* __restrict__ sums)
{
  constexpr int P = H * H, W = H;
  constexpr int LW = (H == 16) ? 4 : ((H == 8) ? 3 : 2);
  constexpr bool HALO = (IMGS == 1);
  constexpr int MROWS = IMGS * P;
  constexpr int WM = MROWS / WAVES_M;
  constexpr int M_rep = WM / 16, N_rep = WN / 16;
  constexpr int COB = WAVES_N * WN;
  constexpr int PW = H + 2;
  constexpr int ASZ = HALO ? PW * PW * CIN * 2 : MROWS * CIN * 2;
  constexpr int BCH = CS * COB * 2;
  constexpr int CH = CIN / CS;
  constexpr int NS = 9 * CH;
  constexpr int BR = (CS * COB) / 4096;
  static_assert(COB * NBLK == COUT, "n");
  static_assert(WAVES_M * WAVES_N == 8, "w");
  static_assert(ASZ + 3 * BCH <= 163840 / 2, "lds");
  static_assert((CS * COB) % 4096 == 0, "br");

  const int tid = threadIdx.x;
  const int l = tid & 63, l15 = l & 15, lq = l >> 4;
  const int wid = tid >> 6;
  const int wn = wid % WAVES_N, wm = wid / WAVES_N;
  const int img0 = (bid / NBLK) * IMGS;
  const int half = bid % NBLK;
  const int co0b = half * COB;
  const int wm0 = wm * WM;
  const int co = co0b + wn * WN;

  auto stageB = [&](int buf, int s) {
    int tap = s / CH, ch = s % CH;
#pragma unroll
    for (int r = 0; r < BR; ++r) {
      int j = r * 512 + tid;
      int ci8 = ch * (CS / 8) + j / COB, c = j % COB;
      const char* gp = (const char*)wpk +
          ((size_t)((tap * (CIN / 8) + ci8) * COUT + co0b + c) << 4);
      char* lp = lds + ASZ + buf * BCH + ((r * 512 + (tid & 448)) << 4);
      gload_lds16(gp, lp);
    }
  };

  stageB(0, 0);
  stageB(1, 1);

  if constexpr (HALO) {
    for (int i = tid * 16; i < ASZ; i += 8192)
      *(int4*)(lds + i) = make_int4(0, 0, 0, 0);
    __syncthreads();
    constexpr int NCH = P * CIN / 8;
    for (int i = tid; i < NCH; i += 512) {
      int pix = i / (CIN / 8), c8 = i % (CIN / 8);
      const char* gp = (const char*)in + (((size_t)img0 * P + pix) * CIN + c8 * 8) * 2;
      int cell = ((pix >> LW) + 1) * PW + (pix & (W - 1)) + 1;
      int lb = ((cell * CIN + c8 * 8) << 1) ^ ((cell & 7) << 4);
      *(short8*)(lds + lb) = *(const short8*)gp;
    }
  } else {
    constexpr int NCH = MROWS * CIN / 8;
    for (int i = tid; i < NCH; i += 512) {
      int row = i / (CIN / 8), c8 = i % (CIN / 8);
      const char* gp = (const char*)in + ((size_t)img0 * P * CIN + (size_t)i * 8) * 2;
      int lb = ((row * CIN + c8 * 8) << 1) ^ ((row & 7) << 4);
      *(short8*)(lds + lb) = *(const short8*)gp;
    }
  }
  __syncthreads();   // A visible; drains prologue B chunks 0,1 (one-time)

  f32x4 acc[M_rep][N_rep];
#pragma unroll
  for (int m = 0; m < M_rep; ++m)
#pragma unroll
    for (int n = 0; n < N_rep; ++n)
#pragma unroll
      for (int r = 0; r < 4; ++r) acc[m][n][r] = 0.f;

  int ym[M_rep], xm[M_rep], imb[M_rep];
#pragma unroll
  for (int m = 0; m < M_rep; ++m) {
    int rb2 = wm0 + m * 16;
    imb[m] = rb2 / P;
    int pp = rb2 % P + l15;
    ym[m] = pp >> LW;
    xm[m] = pp & (W - 1);
  }

  int rb = 0;
  for (int s = 0; s < NS; ++s) {
    const int tap = s / CH;
    const int dy = tap / 3, dx = tap % 3;
    if (s + 1 < NS) wait_vm<BR>(); else wait_vm<0>();
    barrier_mem();
    if (s + 2 < NS) { int sb = rb + 2; if (sb >= 3) sb -= 3; stageB(sb, s + 2); }

    int ab[M_rep]; bool av[M_rep];
#pragma unroll
    for (int m = 0; m < M_rep; ++m) {
      if constexpr (HALO) {
        ab[m] = (ym[m] + dy) * PW + xm[m] + dx;
        av[m] = true;
      } else {
        int sy = ym[m] + dy - 1, sx = xm[m] + dx - 1;
        av[m] = ((unsigned)sy < (unsigned)W) & ((unsigned)sx < (unsigned)W);
        ab[m] = imb[m] * P + sy * W + sx;
      }
    }
#pragma unroll
    for (int c2 = 0; c2 < CS / 32; ++c2) {
      const int cc = (s % CH) * (CS / 32) + c2;
      bf16x8 af[M_rep], bfr[N_rep];
#pragma unroll
      for (int m = 0; m < M_rep; ++m) {
        int lb = ((ab[m] * CIN + cc * 32 + lq * 8) << 1) ^ ((ab[m] & 7) << 4);
        if constexpr (HALO) {
          af[m] = *(const bf16x8*)(lds + lb);
        } else {
          short8 t{};
          if (av[m]) t = *(const short8*)(lds + lb);
          af[m] = __builtin_bit_cast(bf16x8, t);
        }
      }
#pragma unroll
      for (int n = 0; n < N_rep; ++n)
        bfr[n] = *(const bf16x8*)(lds + ASZ + rb * BCH +
                   (((c2 * 4 + lq) * COB + wn * WN + n * 16 + l15) << 4));
      __builtin_amdgcn_s_setprio(1);
#pragma unroll
      for (int m = 0; m < M_rep; ++m)
#pragma unroll
        for (int n = 0; n < N_rep; ++n)
          acc[m][n] = __builtin_amdgcn_mfma_f32_16x16x32_bf16(af[m], bfr[n], acc[m][n], 0, 0, 0);
      __builtin_amdgcn_s_setprio(0);
    }
    rb = (rb == 2) ? 0 : rb + 1;
  }

  if constexpr (STATS) {
    __syncthreads();
    float* sbuf = (float*)lds;
    for (int i = tid; i < 2 * COB; i += 512) sbuf[i] = 0.f;
    __syncthreads();
#pragma unroll
    for (int n = 0; n < N_rep; ++n) {
      float s1 = 0.f, s2 = 0.f;
#pragma unroll
      for (int m = 0; m < M_rep; ++m)
#pragma unroll
        for (int r = 0; r < 4; ++r) { float v = acc[m][n][r]; s1 += v; s2 += v * v; }
      s1 += __shfl_xor(s1, 16); s2 += __shfl_xor(s2, 16);
      s1 += __shfl_xor(s1, 32); s2 += __shfl_xor(s2, 32);
      if (lq == 0) {
        int cg = wn * WN + n * 16 + l15;
        atomicAdd(&sbuf[2 * cg], s1);
        atomicAdd(&sbuf[2 * cg + 1], s2);
      }
    }
    __syncthreads();
    for (int i = tid; i < 2 * COB; i += 512) atomicAdd(&sums[2 * co0b + i], sbuf[i]);
  }

  if constexpr (EPI == EP_RAW) {
#pragma unroll
    for (int m = 0; m < M_rep; ++m)
#pragma unroll
      for (int n = 0; n < N_rep; ++n)
#pragma unroll
        for (int r = 0; r < 4; ++r) {
          int pix = wm0 + m * 16 + lq * 4 + r;   // spans IMGS contiguous images
          bout[((size_t)img0 * P + pix) * COUT + co + n * 16 + l15] = f2bf(acc[m][n][r]);
        }
  } else if constexpr (EPI == EP_E1) {
    // fout=r1 (RMW), bout=e1b ; 8x8 result -> up2 to 16x16 ; IMGS images/block
#pragma unroll
    for (int m = 0; m < M_rep; ++m) {
      int rb2 = wm0 + m * 16;
      const int ime = img0 + rb2 / P;
      const int prow = rb2 % P;
#pragma unroll
      for (int n = 0; n < N_rep; ++n)
#pragma unroll
        for (int r = 0; r < 4; ++r) {
          int pix = prow + lq * 4 + r;
          int y = pix >> 3, x = pix & 7;
          int cg = co + n * 16 + l15;
          float t = tanhf(acc[m][n][r]);
#pragma unroll
          for (int d2 = 0; d2 < 4; ++d2) {
            size_t idx = ((size_t)ime * 256 + (2 * y + (d2 >> 1)) * 16 + 2 * x + (d2 & 1)) * 64 + cg;
            float rv = fout[idx];
            float e = rv - t;
            bout[idx] = f2bf(e);
            fout[idx] = fmaxf(rv - LRr * e, 0.f);
          }
        }
    }
  } else if constexpr (EPI == EP_E2) {
    // fout=r2 (read-only), bout=e2b ; 4x4 -> up2 to 8x8 ; IMGS images/block
#pragma unroll
    for (int m = 0; m < M_rep; ++m) {
      const int ime = img0 + imb[m];
#pragma unroll
      for (int n = 0; n < N_rep; ++n)
#pragma unroll
        for (int r = 0; r < 4; ++r) {
          int pix = lq * 4 + r;
          int y = pix >> 2, x = pix & 3;
          int cg = co + n * 16 + l15;
          float t = tanhf(acc[m][n][r]);
#pragma unroll
          for (int d2 = 0; d2 < 4; ++d2) {
            size_t idx = ((size_t)ime * 64 + (2 * y + (d2 >> 1)) * 8 + 2 * x + (d2 & 1)) * 128 + cg;
            bout[idx] = f2bf(fout[idx] - t);
          }
        }
    }
  } else if constexpr (EPI == EP_P2) {
    // fout=r2 (RMW), bout=r2b, aux=e2b ; pool 16x16 -> 8x8, in-register
#pragma unroll
    for (int m = 0; m < M_rep; m += 2)
#pragma unroll
      for (int n = 0; n < N_rep; ++n)
#pragma unroll
        for (int r0 = 0; r0 < 4; r0 += 2) {
          float sum = acc[m][n][r0] + acc[m][n][r0 + 1] + acc[m + 1][n][r0] + acc[m + 1][n][r0 + 1];
          int yo = ((wm0 >> 4) + m) >> 1;
          int xo = 2 * lq + (r0 >> 1);
          int cg = co + n * 16 + l15;
          size_t idx = ((size_t)img0 * 64 + yo * 8 + xo) * 128 + cg;
          float old = fout[idx];
          float d = 0.25f * sum - bf2f(aux[idx]);
          float nv = fmaxf(fmaf(LRr, d, old), 0.f);
          fout[idx] = nv;
          bout[idx] = f2bf(nv);
        }
  } else {
    // EP_P3: fout=r3 (RMW), bout=r3b ; pool 8x8 -> 4x4 via shfl_xor(32)
#pragma unroll
    for (int m = 0; m < M_rep; ++m) {
      int pb = wm0 + m * 16;
      int iml = pb / P;
      int yo = (pb % P) >> 4;
#pragma unroll
      for (int n = 0; n < N_rep; ++n)
#pragma unroll
        for (int r0 = 0; r0 < 4; r0 += 2) {
          float sx = acc[m][n][r0] + acc[m][n][r0 + 1];
          float sum = sx + __shfl_xor(sx, 32);
          if (l < 32) {
            int xo = 2 * (lq & 1) + (r0 >> 1);
            int cg = co + n * 16 + l15;
            size_t idx = ((size_t)(img0 + iml) * 16 + yo * 4 + xo) * COUT + cg;
            float nv = fmaxf(fmaf(LRr, 0.25f * sum, fout[idx]), 0.f);
            fout[idx] = nv;
            bout[idx] = f2bf(nv);
          }
        }
    }
  }
}

// FF layer2: conv(r1b,W2) raw + stats. 66KB LDS, grid 512.
__global__ __launch_bounds__(512) void ff2_k(const u16* __restrict__ in, const u16* __restrict__ wpk,
                                             u16* __restrict__ outb, float* __restrict__ sums) {
  __shared__ __align__(16) char lds[66048];
  gemm_body<16, 64, 128, 4, 2, 32, 2, 64, 1, EP_RAW, true>(
      blockIdx.x, lds, in, wpk, nullptr, outb, nullptr, sums);
}

// FF layer3: conv(r2b,W3) raw + stats. 2 imgs/block, 80KB, grid 256.
__global__ __launch_bounds__(512) void ff3_k(const u16* __restrict__ in, const u16* __restrict__ wpk,
                                             u16* __restrict__ outb, float* __restrict__ sums) {
  __shared__ __align__(16) char lds[81920];
  gemm_body<8, 128, 256, 4, 2, 64, 2, 64, 2, EP_RAW, true>(
      blockIdx.x, lds, in, wpk, nullptr, outb, nullptr, sums);
}

// merged E1 (256 blocks, 1 img, halo) + E2 (64 blocks, 4 imgs). grid 320.
__global__ __launch_bounds__(512) void ea_k(const u16* __restrict__ r2b, const u16* __restrict__ P2pk,
                                            float* __restrict__ r1, u16* __restrict__ e1b,
                                            const u16* __restrict__ r3b, const u16* __restrict__ P3pk,
                                            const float* __restrict__ r2, u16* __restrict__ e2b) {
  __shared__ __align__(16) char lds[81920];
  if (blockIdx.x < 256)
    gemm_body<8, 128, 64, 4, 2, 32, 1, 128, 1, EP_E1, false>(
        blockIdx.x, lds, r2b, P2pk, r1, e1b, nullptr, nullptr);
  else
    gemm_body<4, 256, 128, 2, 4, 32, 1, 64, 4, EP_E2, false>(
        blockIdx.x - 256, lds, r3b, P3pk, (float*)r2, e2b, nullptr, nullptr);
}

// merged P2 (512 blocks) + P3 (256 blocks, 2 imgs). 80KB, grid 768.
__global__ __launch_bounds__(512) void pb_k(const u16* __restrict__ e1b, const u16* __restrict__ W2pk,
                                            float* __restrict__ r2, u16* __restrict__ r2b,
                                            const u16* __restrict__ e2b, const u16* __restrict__ W3pk,
                                            float* __restrict__ r3, u16* __restrict__ r3b) {
  __shared__ __align__(16) char lds[81920];
  if (blockIdx.x < 512)
    gemm_body<16, 64, 128, 4, 2, 32, 2, 64, 1, EP_P2, false>(
        blockIdx.x, lds, e1b, W2pk, r2, r2b, e2b, nullptr);
  else
    gemm_body<8, 128, 256, 4, 2, 64, 2, 64, 2, EP_P3, false>(
        blockIdx.x - 512, lds, e2b, W3pk, r3, r3b, nullptr, nullptr);
}

// pack weights -> [tap][ci/8][cout][8] bf16. FLIP: conv-transpose weights.
template<int CI, int CO, bool FLIP>
__global__ __launch_bounds__(256) void pack_k(const float* __restrict__ src, u16* __restrict__ dst) {
  int idx = blockIdx.x * 256 + threadIdx.x;
  int tap = idx / (CI * CO), rem = idx % (CI * CO);
  int ci = rem / CO, c = rem % CO;
  int dy = tap / 3, dx = tap % 3;
  float v = FLIP ? src[((size_t)ci * CO + c) * 9 + (2 - dy) * 3 + (2 - dx)]
                 : src[((size_t)c * CI + ci) * 9 + dy * 3 + dx];
  dst[(((size_t)tap * (CI / 8) + (ci >> 3)) * CO + c) * 8 + (ci & 7)] = f2bf(v);
}

// pack W1 -> [k/8][64][8] with k = tap*3+cc, padded to K=32
__global__ void pack1_k(const float* __restrict__ W1, u16* __restrict__ W1pk) {
  for (int j = threadIdx.x; j < 2048; j += 256) {
    int klo = j & 7, rest = j >> 3;
    int co = rest & 63, k8 = rest >> 6;
    int k = k8 * 8 + klo;
    float v = 0.f;
    if (k < 27) {
      int tap = k / 3, cc = k % 3, dy = tap / 3, dx = tap % 3;
      v = W1[((size_t)(co * 3 + cc) * 3 + dy) * 3 + dx];
    }
    W1pk[j] = f2bf(v);
  }
}

// conv1 via MFMA (im2col K=27->32), fragments built in registers.
template<bool POOL>
__global__ __launch_bounds__(256) void c1_k(const float* __restrict__ x,
                                            const u16* __restrict__ W1pk,
                                            float* __restrict__ sums,
                                            const float* __restrict__ ss,
                                            float* __restrict__ r1,
                                            u16* __restrict__ r1b) {
  __shared__ __align__(16) char lds[28480];
  float* xs = (float*)lds;
  char* Al = lds + 3904;
  char* Bl = lds + 24384;
  const int bid = blockIdx.x;
  const int img = bid >> 2, quad = bid & 3;
  const int ty0 = (quad >> 1) * 16, tx0 = (quad & 1) * 16;
  const int tid = threadIdx.x;
  const int l = tid & 63, l15 = l & 15, lq = l >> 4;
  const int wm = tid >> 6;

  gload_lds16((const char*)W1pk + tid * 16, Bl + ((tid & 192) << 4));
  for (int i = tid; i < 972; i += 256) {
    int xx = i % 18, yy = (i / 18) % 18, cc = i / 324;
    int gy = ty0 + yy - 1, gx = tx0 + xx - 1;
    float v = 0.f;
    if (gy >= 0 && gy < 32 && gx >= 0 && gx < 32)
      v = x[((size_t)(img * 3 + cc) * 32 + gy) * 32 + gx];
    xs[i] = v;
  }
  __syncthreads();
  {
    const int ty = tid >> 4, tx = tid & 15;
#pragma unroll
    for (int i = 0; i < 4; ++i) {
      short8 v{};
#pragma unroll
      for (int j = 0; j < 8; ++j) {
        constexpr int base[4] = {0, 8, 16, 24};
        int k = base[i] + j;
        if (k < 27) {
          int tap = k / 3, cc = k % 3;
          v[j] = (short)f2bf(xs[cc * 324 + (ty + tap / 3) * 18 + tx + tap % 3]);
        }
      }
      *(short8*)(Al + tid * 80 + i * 16) = v;
    }
  }
  __syncthreads();

  f32x4 acc[4][4];
  bf16x8 af[4], bfr[4];
#pragma unroll
  for (int m = 0; m < 4; ++m) {
    int pix = wm * 64 + m * 16 + l15;
    af[m] = *(const bf16x8*)(Al + pix * 80 + lq * 16);
  }
#pragma unroll
  for (int n = 0; n < 4; ++n)
    bfr[n] = *(const bf16x8*)(Bl + ((lq * 64 + n * 16 + l15) << 4));
#pragma unroll
  for (int m = 0; m < 4; ++m)
#pragma unroll
    for (int n = 0; n < 4; ++n) {
      f32x4 z = {0.f, 0.f, 0.f, 0.f};
      acc[m][n] = __builtin_amdgcn_mfma_f32_16x16x32_bf16(af[m], bfr[n], z, 0, 0, 0);
    }

  if constexpr (!POOL) {
    float* sbuf = (float*)lds;
    __syncthreads();
    for (int i = tid; i < 128; i += 256) sbuf[i] = 0.f;
    __syncthreads();
#pragma unroll
    for (int n = 0; n < 4; ++n) {
      float s1 = 0.f, s2 = 0.f;
#pragma unroll
      for (int m = 0; m < 4; ++m)
#pragma unroll
        for (int r = 0; r < 4; ++r) { float v = acc[m][n][r]; s1 += v; s2 += v * v; }
      s1 += __shfl_xor(s1, 16); s2 += __shfl_xor(s2, 16);
      s1 += __shfl_xor(s1, 32); s2 += __shfl_xor(s2, 32);
      if (lq == 0) {
        int cg = n * 16 + l15;
        atomicAdd(&sbuf[2 * cg], s1);
        atomicAdd(&sbuf[2 * cg + 1], s2);
      }
    }
    __syncthreads();
    if (tid < 128) atomicAdd(&sums[tid], sbuf[tid]);
  } else {
    float ssv[4], ssh[4];
#pragma unroll
    for (int n = 0; n < 4; ++n) {
      ssv[n] = ss[n * 16 + l15];
      ssh[n] = ss[64 + n * 16 + l15];
    }
#pragma unroll
    for (int m = 0; m < 4; m += 2)
#pragma unroll
      for (int n = 0; n < 4; ++n)
#pragma unroll
        for (int r0 = 0; r0 < 4; r0 += 2) {
          float a0 = fmaf(acc[m][n][r0], ssv[n], ssh[n]);
          float a1 = fmaf(acc[m][n][r0 + 1], ssv[n], ssh[n]);
          float b0 = fmaf(acc[m + 1][n][r0], ssv[n], ssh[n]);
          float b1 = fmaf(acc[m + 1][n][r0 + 1], ssv[n], ssh[n]);
          float v = fmaxf(fmaxf(fmaxf(a0, a1), fmaxf(b0, b1)), 0.f);
          int py = (ty0 >> 1) + ((wm * 4 + m) >> 1);
          int px = (tx0 >> 1) + ((lq * 4 + r0) >> 1);
          size_t idx = ((size_t)img * 256 + py * 16 + px) * 64 + n * 16 + l15;
          r1[idx] = v;
          r1b[idx] = f2bf(v);
        }
  }
}

__global__ void ss_k(const float* __restrict__ sums, const float* __restrict__ g,
                     const float* __restrict__ b, float* __restrict__ ss, int C, float invN) {
  int c = blockIdx.x * 64 + threadIdx.x;
  if (c < C) {
    float m = sums[2 * c] * invN;
    float var = sums[2 * c + 1] * invN - m * m;
    float sc = g[c] * rsqrtf(var + 1e-5f);
    ss[c] = sc;
    ss[C + c] = b[c] - m * sc;
  }
}

template<int C, int H>
__global__ __launch_bounds__(256) void bnpool_k(const u16* __restrict__ t, const float* __restrict__ ss,
                                                float* __restrict__ r, u16* __restrict__ rb) {
  constexpr int HP = H / 2, C4 = C / 4;
  int idx = blockIdx.x * 256 + threadIdx.x;
  int c4 = idx % C4, po = idx / C4;
  int xo = po % HP, t2 = po / HP;
  int yo = t2 % HP, img = t2 / HP;
  const u16* p0 = t + (((size_t)img * H + 2 * yo) * H + 2 * xo) * C + c4 * 4;
  u16x4 a = *(const u16x4*)p0, b = *(const u16x4*)(p0 + C);
  u16x4 c_ = *(const u16x4*)(p0 + H * C), d = *(const u16x4*)(p0 + H * C + C);
  f32x4 sc = *(const f32x4*)(ss + c4 * 4);
  f32x4 sh = *(const f32x4*)(ss + C + c4 * 4);
  f32x4 o;
#pragma unroll
  for (int j = 0; j < 4; ++j) {
    float v0 = fmaf(bf2f(a[j]), sc[j], sh[j]);
    float v1 = fmaf(bf2f(b[j]), sc[j], sh[j]);
    float v2 = fmaf(bf2f(c_[j]), sc[j], sh[j]);
    float v3 = fmaf(bf2f(d[j]), sc[j], sh[j]);
    o[j] = fmaxf(fmaxf(fmaxf(v0, v1), fmaxf(v2, v3)), 0.f);
  }
  *(f32x4*)(r + (size_t)idx * 4) = o;
  u16x4 ob;
#pragma unroll
  for (int j = 0; j < 4; ++j) ob[j] = f2bf(o[j]);
  *(u16x4*)(rb + (size_t)idx * 4) = ob;
}

template<int P, int C, int CHUNKS>
__global__ __launch_bounds__(256) void tr_k(const float* __restrict__ in, float* __restrict__ out) {
  constexpr int TP = P / CHUNKS;
  __shared__ float tl[TP][C + 1];
  const int img = blockIdx.x, ch = blockIdx.y;
  const float* ip = in + (size_t)img * P * C;
  float* op = out + (size_t)img * P * C;
  for (int i = threadIdx.x; i < TP * C / 4; i += 256) {
    int p = i / (C / 4), c4 = i % (C / 4);
    f32x4 v = *(const f32x4*)&ip[(size_t)(ch * TP + p) * C + c4 * 4];
#pragma unroll
    for (int j = 0; j < 4; ++j) tl[p][c4 * 4 + j] = v[j];
  }
  __syncthreads();
  for (int i = threadIdx.x; i < TP * C; i += 256) {
    int c = i / TP, p = i % TP;
    op[(size_t)c * P + ch * TP + p] = tl[p][c];
  }
}

extern "C" void kernel_launch(void* const* d_in, const int* in_sizes, int n_in,
                              void* d_out, int out_size, void* d_ws, size_t ws_size,
                              hipStream_t stream) {
  const float* x  = (const float*)d_in[0];
  const float* W1 = (const float*)d_in[1];
  const float* W2 = (const float*)d_in[2];
  const float* W3 = (const float*)d_in[3];
  const float* P2 = (const float*)d_in[4];
  const float* P3 = (const float*)d_in[5];
  const float* g1 = (const float*)d_in[6];
  const float* b1 = (const float*)d_in[7];
  const float* g2 = (const float*)d_in[8];
  const float* b2 = (const float*)d_in[9];
  const float* g3 = (const float*)d_in[10];
  const float* b3 = (const float*)d_in[11];

  char* w = (char*)d_ws;
  auto alloc = [&](size_t n) { char* p = w; w += (n + 255) & ~(size_t)255; return p; };
  float* r1  = (float*)alloc(16777216);  // NHWC [256,16,16,64]
  float* r2  = (float*)alloc(8388608);   // [256,8,8,128]
  float* r3  = (float*)alloc(4194304);   // [256,4,4,256]
  u16* r1b   = (u16*)alloc(8388608);
  u16* r2b   = (u16*)alloc(4194304);
  u16* r3b   = (u16*)alloc(2097152);
  u16* W2pk  = (u16*)alloc(147456);
  u16* W3pk  = (u16*)alloc(589824);
  u16* P2pk  = (u16*)alloc(147456);
  u16* P3pk  = (u16*)alloc(589824);
  u16* W1pk  = (u16*)alloc(4096);
  float* sums = (float*)alloc(3584);
  float* ssb  = (float*)alloc(3584);
  char* S = alloc(33554432);             // t2 16MB / t3 8MB / e1b 8MB / e2b 4MB
  u16* t2 = (u16*)S;
  u16* t3 = (u16*)S;
  u16* e1b = (u16*)S;
  u16* e2b = (u16*)(S + 8388608);

  hipMemsetAsync(sums, 0, 3584, stream);

  pack_k<64, 128, false><<<288, 256, 0, stream>>>(W2, W2pk);
  pack_k<128, 256, false><<<1152, 256, 0, stream>>>(W3, W3pk);
  pack_k<128, 64, true><<<288, 256, 0, stream>>>(P2, P2pk);
  pack_k<256, 128, true><<<1152, 256, 0, stream>>>(P3, P3pk);
  pack1_k<<<1, 256, 0, stream>>>(W1, W1pk);

  // ---- feed-forward ----
  c1_k<false><<<1024, 256, 0, stream>>>(x, W1pk, sums, nullptr, nullptr, nullptr);
  ss_k<<<1, 64, 0, stream>>>(sums, g1, b1, ssb, 64, 1.f / 262144.f);
  c1_k<true><<<1024, 256, 0, stream>>>(x, W1pk, nullptr, ssb, r1, r1b);

  ff2_k<<<512, 512, 0, stream>>>(r1b, W2pk, t2, sums + 128);
  ss_k<<<2, 64, 0, stream>>>(sums + 128, g2, b2, ssb + 128, 128, 1.f / 65536.f);
  bnpool_k<128, 16><<<2048, 256, 0, stream>>>(t2, ssb + 128, r2, r2b);

  ff3_k<<<256, 512, 0, stream>>>(r2b, W3pk, t3, sums + 384);
  ss_k<<<4, 64, 0, stream>>>(sums + 384, g3, b3, ssb + 384, 256, 1.f / 16384.f);
  bnpool_k<256, 8><<<1024, 256, 0, stream>>>(t3, ssb + 384, r3, r3b);

  // ---- predictive-coding iterations (2 dispatches / iter) ----
  for (int it = 0; it < 10; ++it) {
    ea_k<<<320, 512, 0, stream>>>(r2b, P2pk, r1, e1b, r3b, P3pk, r2, e2b);
    pb_k<<<768, 512, 0, stream>>>(e1b, W2pk, r2, r2b, e2b, W3pk, r3, r3b);
  }

  // ---- NHWC -> NCHW outputs ----
  float* out = (float*)d_out;
  tr_k<256, 64, 4><<<dim3(256, 4), 256, 0, stream>>>(r1, out);
  tr_k<64, 128, 1><<<dim3(256, 1), 256, 0, stream>>>(r2, out + 4194304);
  tr_k<16, 256, 1><<<dim3(256, 1), 256, 0, stream>>>(r3, out + 6291456);
}

// Round 16
// 662.700 us; speedup vs baseline: 1.1188x; 1.0014x over previous
//
#include <hip/hip_runtime.h>
#include <cstddef>
#include <cstdint>

#define LRr 0.02f

typedef unsigned short u16;
typedef __attribute__((ext_vector_type(8))) __bf16 bf16x8;
typedef __attribute__((ext_vector_type(8))) short short8;
typedef __attribute__((ext_vector_type(4))) float f32x4;
typedef __attribute__((ext_vector_type(4))) u16 u16x4;

static __device__ __forceinline__ u16 f2bf(float f) {
  union { float f; unsigned int u; } v{f};
  unsigned int r = (v.u + 0x7FFFu + ((v.u >> 16) & 1u)) >> 16;
  return (u16)r;
}
static __device__ __forceinline__ float bf2f(u16 h) {
  union { unsigned int u; float f; } v{(unsigned int)h << 16};
  return v.f;
}

static __device__ __forceinline__ void gload_lds16(const void* g, void* l) {
  __builtin_amdgcn_global_load_lds(
      (const __attribute__((address_space(1))) unsigned int*)g,
      (__attribute__((address_space(3))) unsigned int*)l, 16, 0, 0);
}

// counted waitcnt: allow N outstanding VMEM ops
template<int N> static __device__ __forceinline__ void wait_vm() {
  if constexpr (N <= 0)      asm volatile("s_waitcnt vmcnt(0)" ::: "memory");
  else if constexpr (N == 1) asm volatile("s_waitcnt vmcnt(1)" ::: "memory");
  else if constexpr (N == 2) asm volatile("s_waitcnt vmcnt(2)" ::: "memory");
  else if constexpr (N == 3) asm volatile("s_waitcnt vmcnt(3)" ::: "memory");
  else if constexpr (N == 4) asm volatile("s_waitcnt vmcnt(4)" ::: "memory");
  else                       asm volatile("s_waitcnt vmcnt(6)" ::: "memory");
}
static __device__ __forceinline__ void barrier_mem() {
  asm volatile("s_barrier" ::: "memory");
}

enum { EP_RAW = 0, EP_E1 = 1, EP_E2 = 2, EP_P2 = 3, EP_P3 = 4 };

// Implicit-GEMM 3x3 conv, pad=1, NHWC bf16 — 512-thread / 8-wave blocks.
// B triple-buffered per CS-chunk via global_load_lds + counted vmcnt(BR) +
// raw s_barrier; s_setprio(1) around the MFMA cluster (T5, r15-verified).
// r16: LAST variants of E1/P2/P3 write final r1/r2/r3 directly to d_out in
// NCHW fp32 (same scalar-store count as the NHWC path), eliminating tr_k.
template<int H, int CIN, int COUT, int WAVES_M, int WAVES_N, int WN, int NBLK,
         int CS, int IMGS, int EPI, bool STATS, bool LAST>
__device__ __forceinline__ void gemm_body(
    int bid, char* lds,
    const u16* __restrict__ in, const u16* __restrict__ wpk,
    float* __restrict__ fout, u16* __restrict__ bout,
    const u16* __restrict__ aux, float* __restrict__ sums,
    float* __restrict__ nco)
{
  constexpr int P = H * H, W = H;
  constexpr int LW = (H == 16) ? 4 : ((H == 8) ? 3 : 2);
  constexpr bool HALO = (IMGS == 1);
  constexpr int MROWS = IMGS * P;
  constexpr int WM = MROWS / WAVES_M;
  constexpr int M_rep = WM / 16, N_rep = WN / 16;
  constexpr int COB = WAVES_N * WN;
  constexpr int PW = H + 2;
  constexpr int ASZ = HALO ? PW * PW * CIN * 2 : MROWS * CIN * 2;
  constexpr int BCH = CS * COB * 2;
  constexpr int CH = CIN / CS;
  constexpr int NS = 9 * CH;
  constexpr int BR = (CS * COB) / 4096;
  static_assert(COB * NBLK == COUT, "n");
  static_assert(WAVES_M * WAVES_N == 8, "w");
  static_assert(ASZ + 3 * BCH <= 163840 / 2, "lds");
  static_assert((CS * COB) % 4096 == 0, "br");

  const int tid = threadIdx.x;
  const int l = tid & 63, l15 = l & 15, lq = l >> 4;
  const int wid = tid >> 6;
  const int wn = wid % WAVES_N, wm = wid / WAVES_N;
  const int img0 = (bid / NBLK) * IMGS;
  const int half = bid % NBLK;
  const int co0b = half * COB;
  const int wm0 = wm * WM;
  const int co = co0b + wn * WN;

  auto stageB = [&](int buf, int s) {
    int tap = s / CH, ch = s % CH;
#pragma unroll
    for (int r = 0; r < BR; ++r) {
      int j = r * 512 + tid;
      int ci8 = ch * (CS / 8) + j / COB, c = j % COB;
      const char* gp = (const char*)wpk +
          ((size_t)((tap * (CIN / 8) + ci8) * COUT + co0b + c) << 4);
      char* lp = lds + ASZ + buf * BCH + ((r * 512 + (tid & 448)) << 4);
      gload_lds16(gp, lp);
    }
  };

  stageB(0, 0);
  stageB(1, 1);

  if constexpr (HALO) {
    for (int i = tid * 16; i < ASZ; i += 8192)
      *(int4*)(lds + i) = make_int4(0, 0, 0, 0);
    __syncthreads();
    constexpr int NCH = P * CIN / 8;
    for (int i = tid; i < NCH; i += 512) {
      int pix = i / (CIN / 8), c8 = i % (CIN / 8);
      const char* gp = (const char*)in + (((size_t)img0 * P + pix) * CIN + c8 * 8) * 2;
      int cell = ((pix >> LW) + 1) * PW + (pix & (W - 1)) + 1;
      int lb = ((cell * CIN + c8 * 8) << 1) ^ ((cell & 7) << 4);
      *(short8*)(lds + lb) = *(const short8*)gp;
    }
  } else {
    constexpr int NCH = MROWS * CIN / 8;
    for (int i = tid; i < NCH; i += 512) {
      int row = i / (CIN / 8), c8 = i % (CIN / 8);
      const char* gp = (const char*)in + ((size_t)img0 * P * CIN + (size_t)i * 8) * 2;
      int lb = ((row * CIN + c8 * 8) << 1) ^ ((row & 7) << 4);
      *(short8*)(lds + lb) = *(const short8*)gp;
    }
  }
  __syncthreads();   // A visible; drains prologue B chunks 0,1 (one-time)

  f32x4 acc[M_rep][N_rep];
#pragma unroll
  for (int m = 0; m < M_rep; ++m)
#pragma unroll
    for (int n = 0; n < N_rep; ++n)
#pragma unroll
      for (int r = 0; r < 4; ++r) acc[m][n][r] = 0.f;

  int ym[M_rep], xm[M_rep], imb[M_rep];
#pragma unroll
  for (int m = 0; m < M_rep; ++m) {
    int rb2 = wm0 + m * 16;
    imb[m] = rb2 / P;
    int pp = rb2 % P + l15;
    ym[m] = pp >> LW;
    xm[m] = pp & (W - 1);
  }

  int rb = 0;
  for (int s = 0; s < NS; ++s) {
    const int tap = s / CH;
    const int dy = tap / 3, dx = tap % 3;
    if (s + 1 < NS) wait_vm<BR>(); else wait_vm<0>();
    barrier_mem();
    if (s + 2 < NS) { int sb = rb + 2; if (sb >= 3) sb -= 3; stageB(sb, s + 2); }

    int ab[M_rep]; bool av[M_rep];
#pragma unroll
    for (int m = 0; m < M_rep; ++m) {
      if constexpr (HALO) {
        ab[m] = (ym[m] + dy) * PW + xm[m] + dx;
        av[m] = true;
      } else {
        int sy = ym[m] + dy - 1, sx = xm[m] + dx - 1;
        av[m] = ((unsigned)sy < (unsigned)W) & ((unsigned)sx < (unsigned)W);
        ab[m] = imb[m] * P + sy * W + sx;
      }
    }
#pragma unroll
    for (int c2 = 0; c2 < CS / 32; ++c2) {
      const int cc = (s % CH) * (CS / 32) + c2;
      bf16x8 af[M_rep], bfr[N_rep];
#pragma unroll
      for (int m = 0; m < M_rep; ++m) {
        int lb = ((ab[m] * CIN + cc * 32 + lq * 8) << 1) ^ ((ab[m] & 7) << 4);
        if constexpr (HALO) {
          af[m] = *(const bf16x8*)(lds + lb);
        } else {
          short8 t{};
          if (av[m]) t = *(const short8*)(lds + lb);
          af[m] = __builtin_bit_cast(bf16x8, t);
        }
      }
#pragma unroll
      for (int n = 0; n < N_rep; ++n)
        bfr[n] = *(const bf16x8*)(lds + ASZ + rb * BCH +
                   (((c2 * 4 + lq) * COB + wn * WN + n * 16 + l15) << 4));
      __builtin_amdgcn_s_setprio(1);
#pragma unroll
      for (int m = 0; m < M_rep; ++m)
#pragma unroll
        for (int n = 0; n < N_rep; ++n)
          acc[m][n] = __builtin_amdgcn_mfma_f32_16x16x32_bf16(af[m], bfr[n], acc[m][n], 0, 0, 0);
      __builtin_amdgcn_s_setprio(0);
    }
    rb = (rb == 2) ? 0 : rb + 1;
  }

  if constexpr (STATS) {
    __syncthreads();
    float* sbuf = (float*)lds;
    for (int i = tid; i < 2 * COB; i += 512) sbuf[i] = 0.f;
    __syncthreads();
#pragma unroll
    for (int n = 0; n < N_rep; ++n) {
      float s1 = 0.f, s2 = 0.f;
#pragma unroll
      for (int m = 0; m < M_rep; ++m)
#pragma unroll
        for (int r = 0; r < 4; ++r) { float v = acc[m][n][r]; s1 += v; s2 += v * v; }
      s1 += __shfl_xor(s1, 16); s2 += __shfl_xor(s2, 16);
      s1 += __shfl_xor(s1, 32); s2 += __shfl_xor(s2, 32);
      if (lq == 0) {
        int cg = wn * WN + n * 16 + l15;
        atomicAdd(&sbuf[2 * cg], s1);
        atomicAdd(&sbuf[2 * cg + 1], s2);
      }
    }
    __syncthreads();
    for (int i = tid; i < 2 * COB; i += 512) atomicAdd(&sums[2 * co0b + i], sbuf[i]);
  }

  if constexpr (EPI == EP_RAW) {
#pragma unroll
    for (int m = 0; m < M_rep; ++m)
#pragma unroll
      for (int n = 0; n < N_rep; ++n)
#pragma unroll
        for (int r = 0; r < 4; ++r) {
          int pix = wm0 + m * 16 + lq * 4 + r;   // spans IMGS contiguous images
          bout[((size_t)img0 * P + pix) * COUT + co + n * 16 + l15] = f2bf(acc[m][n][r]);
        }
  } else if constexpr (EPI == EP_E1) {
    // fout=r1 ws (RMW), bout=e1b ; LAST: new r1 -> nco NCHW [256,64,16,16]
#pragma unroll
    for (int m = 0; m < M_rep; ++m) {
      int rb2 = wm0 + m * 16;
      const int ime = img0 + rb2 / P;
      const int prow = rb2 % P;
#pragma unroll
      for (int n = 0; n < N_rep; ++n)
#pragma unroll
        for (int r = 0; r < 4; ++r) {
          int pix = prow + lq * 4 + r;
          int y = pix >> 3, x = pix & 7;
          int cg = co + n * 16 + l15;
          float t = tanhf(acc[m][n][r]);
#pragma unroll
          for (int d2 = 0; d2 < 4; ++d2) {
            int row = (2 * y + (d2 >> 1)) * 16 + 2 * x + (d2 & 1);
            size_t idx = ((size_t)ime * 256 + row) * 64 + cg;
            float rv = fout[idx];
            float e = rv - t;
            bout[idx] = f2bf(e);
            float nv = fmaxf(rv - LRr * e, 0.f);
            if constexpr (LAST)
              nco[((size_t)ime * 64 + cg) * 256 + row] = nv;
            else
              fout[idx] = nv;
          }
        }
    }
  } else if constexpr (EPI == EP_E2) {
    // fout=r2 (read-only), bout=e2b ; 4x4 -> up2 to 8x8 ; IMGS images/block
#pragma unroll
    for (int m = 0; m < M_rep; ++m) {
      const int ime = img0 + imb[m];
#pragma unroll
      for (int n = 0; n < N_rep; ++n)
#pragma unroll
        for (int r = 0; r < 4; ++r) {
          int pix = lq * 4 + r;
          int y = pix >> 2, x = pix & 3;
          int cg = co + n * 16 + l15;
          float t = tanhf(acc[m][n][r]);
#pragma unroll
          for (int d2 = 0; d2 < 4; ++d2) {
            size_t idx = ((size_t)ime * 64 + (2 * y + (d2 >> 1)) * 8 + 2 * x + (d2 & 1)) * 128 + cg;
            bout[idx] = f2bf(fout[idx] - t);
          }
        }
    }
  } else if constexpr (EPI == EP_P2) {
    // fout=r2 ws (RMW), bout=r2b, aux=e2b ; LAST: -> nco NCHW [256,128,8,8]
#pragma unroll
    for (int m = 0; m < M_rep; m += 2)
#pragma unroll
      for (int n = 0; n < N_rep; ++n)
#pragma unroll
        for (int r0 = 0; r0 < 4; r0 += 2) {
          float sum = acc[m][n][r0] + acc[m][n][r0 + 1] + acc[m + 1][n][r0] + acc[m + 1][n][r0 + 1];
          int yo = ((wm0 >> 4) + m) >> 1;
          int xo = 2 * lq + (r0 >> 1);
          int cg = co + n * 16 + l15;
          int row = yo * 8 + xo;
          size_t idx = ((size_t)img0 * 64 + row) * 128 + cg;
          float old = fout[idx];
          float d = 0.25f * sum - bf2f(aux[idx]);
          float nv = fmaxf(fmaf(LRr, d, old), 0.f);
          if constexpr (LAST) {
            nco[((size_t)img0 * 128 + cg) * 64 + row] = nv;
          } else {
            fout[idx] = nv;
            bout[idx] = f2bf(nv);
          }
        }
  } else {
    // EP_P3: fout=r3 ws (RMW), bout=r3b ; LAST: -> nco NCHW [256,256,4,4]
#pragma unroll
    for (int m = 0; m < M_rep; ++m) {
      int pb = wm0 + m * 16;
      int iml = pb / P;
      int yo = (pb % P) >> 4;
#pragma unroll
      for (int n = 0; n < N_rep; ++n)
#pragma unroll
        for (int r0 = 0; r0 < 4; r0 += 2) {
          float sx = acc[m][n][r0] + acc[m][n][r0 + 1];
          float sum = sx + __shfl_xor(sx, 32);
          if (l < 32) {
            int xo = 2 * (lq & 1) + (r0 >> 1);
            int cg = co + n * 16 + l15;
            int row = yo * 4 + xo;
            size_t idx = ((size_t)(img0 + iml) * 16 + row) * COUT + cg;
            float nv = fmaxf(fmaf(LRr, 0.25f * sum, fout[idx]), 0.f);
            if constexpr (LAST) {
              nco[((size_t)(img0 + iml) * 256 + cg) * 16 + row] = nv;
            } else {
              fout[idx] = nv;
              bout[idx] = f2bf(nv);
            }
          }
        }
    }
  }
}

// FF layer2: conv(r1b,W2) raw + stats. 66KB LDS, grid 512.
__global__ __launch_bounds__(512) void ff2_k(const u16* __restrict__ in, const u16* __restrict__ wpk,
                                             u16* __restrict__ outb, float* __restrict__ sums) {
  __shared__ __align__(16) char lds[66048];
  gemm_body<16, 64, 128, 4, 2, 32, 2, 64, 1, EP_RAW, true, false>(
      blockIdx.x, lds, in, wpk, nullptr, outb, nullptr, sums, nullptr);
}

// FF layer3: conv(r2b,W3) raw + stats. 2 imgs/block, 80KB, grid 256.
__global__ __launch_bounds__(512) void ff3_k(const u16* __restrict__ in, const u16* __restrict__ wpk,
                                             u16* __restrict__ outb, float* __restrict__ sums) {
  __shared__ __align__(16) char lds[81920];
  gemm_body<8, 128, 256, 4, 2, 64, 2, 64, 2, EP_RAW, true, false>(
      blockIdx.x, lds, in, wpk, nullptr, outb, nullptr, sums, nullptr);
}

// merged E1 (256 blocks, 1 img, halo) + E2 (64 blocks, 4 imgs). grid 320.
// LAST: E1 writes final r1 NCHW to out1.
template<bool LAST>
__global__ __launch_bounds__(512) void ea_k(const u16* __restrict__ r2b, const u16* __restrict__ P2pk,
                                            float* __restrict__ r1, u16* __restrict__ e1b,
                                            const u16* __restrict__ r3b, const u16* __restrict__ P3pk,
                                            const float* __restrict__ r2, u16* __restrict__ e2b,
                                            float* __restrict__ out1) {
  __shared__ __align__(16) char lds[81920];
  if (blockIdx.x < 256)
    gemm_body<8, 128, 64, 4, 2, 32, 1, 128, 1, EP_E1, false, LAST>(
        blockIdx.x, lds, r2b, P2pk, r1, e1b, nullptr, nullptr, out1);
  else
    gemm_body<4, 256, 128, 2, 4, 32, 1, 64, 4, EP_E2, false, false>(
        blockIdx.x - 256, lds, r3b, P3pk, (float*)r2, e2b, nullptr, nullptr, nullptr);
}

// merged P2 (512 blocks) + P3 (256 blocks, 2 imgs). 80KB, grid 768.
// LAST: writes final r2/r3 NCHW to out2/out3.
template<bool LAST>
__global__ __launch_bounds__(512) void pb_k(const u16* __restrict__ e1b, const u16* __restrict__ W2pk,
                                            float* __restrict__ r2, u16* __restrict__ r2b,
                                            const u16* __restrict__ e2b, const u16* __restrict__ W3pk,
                                            float* __restrict__ r3, u16* __restrict__ r3b,
                                            float* __restrict__ out2, float* __restrict__ out3) {
  __shared__ __align__(16) char lds[81920];
  if (blockIdx.x < 512)
    gemm_body<16, 64, 128, 4, 2, 32, 2, 64, 1, EP_P2, false, LAST>(
        blockIdx.x, lds, e1b, W2pk, r2, r2b, e2b, nullptr, out2);
  else
    gemm_body<8, 128, 256, 4, 2, 64, 2, 64, 2, EP_P3, false, LAST>(
        blockIdx.x - 512, lds, e2b, W3pk, r3, r3b, nullptr, nullptr, out3);
}

// pack weights -> [tap][ci/8][cout][8] bf16. FLIP: conv-transpose weights.
template<int CI, int CO, bool FLIP>
__global__ __launch_bounds__(256) void pack_k(const float* __restrict__ src, u16* __restrict__ dst) {
  int idx = blockIdx.x * 256 + threadIdx.x;
  int tap = idx / (CI * CO), rem = idx % (CI * CO);
  int ci = rem / CO, c = rem % CO;
  int dy = tap / 3, dx = tap % 3;
  float v = FLIP ? src[((size_t)ci * CO + c) * 9 + (2 - dy) * 3 + (2 - dx)]
                 : src[((size_t)c * CI + ci) * 9 + dy * 3 + dx];
  dst[(((size_t)tap * (CI / 8) + (ci >> 3)) * CO + c) * 8 + (ci & 7)] = f2bf(v);
}

// pack W1 -> [k/8][64][8] with k = tap*3+cc, padded to K=32
__global__ void pack1_k(const float* __restrict__ W1, u16* __restrict__ W1pk) {
  for (int j = threadIdx.x; j < 2048; j += 256) {
    int klo = j & 7, rest = j >> 3;
    int co = rest & 63, k8 = rest >> 6;
    int k = k8 * 8 + klo;
    float v = 0.f;
    if (k < 27) {
      int tap = k / 3, cc = k % 3, dy = tap / 3, dx = tap % 3;
      v = W1[((size_t)(co * 3 + cc) * 3 + dy) * 3 + dx];
    }
    W1pk[j] = f2bf(v);
  }
}

// conv1 via MFMA (im2col K=27->32), fragments built in registers.
template<bool POOL>
__global__ __launch_bounds__(256) void c1_k(const float* __restrict__ x,
                                            const u16* __restrict__ W1pk,
                                            float* __restrict__ sums,
                                            const float* __restrict__ ss,
                                            float* __restrict__ r1,
                                            u16* __restrict__ r1b) {
  __shared__ __align__(16) char lds[28480];
  float* xs = (float*)lds;
  char* Al = lds + 3904;
  char* Bl = lds + 24384;
  const int bid = blockIdx.x;
  const int img = bid >> 2, quad = bid & 3;
  const int ty0 = (quad >> 1) * 16, tx0 = (quad & 1) * 16;
  const int tid = threadIdx.x;
  const int l = tid & 63, l15 = l & 15, lq = l >> 4;
  const int wm = tid >> 6;

  gload_lds16((const char*)W1pk + tid * 16, Bl + ((tid & 192) << 4));
  for (int i = tid; i < 972; i += 256) {
    int xx = i % 18, yy = (i / 18) % 18, cc = i / 324;
    int gy = ty0 + yy - 1, gx = tx0 + xx - 1;
    float v = 0.f;
    if (gy >= 0 && gy < 32 && gx >= 0 && gx < 32)
      v = x[((size_t)(img * 3 + cc) * 32 + gy) * 32 + gx];
    xs[i] = v;
  }
  __syncthreads();
  {
    const int ty = tid >> 4, tx = tid & 15;
#pragma unroll
    for (int i = 0; i < 4; ++i) {
      short8 v{};
#pragma unroll
      for (int j = 0; j < 8; ++j) {
        constexpr int base[4] = {0, 8, 16, 24};
        int k = base[i] + j;
        if (k < 27) {
          int tap = k / 3, cc = k % 3;
          v[j] = (short)f2bf(xs[cc * 324 + (ty + tap / 3) * 18 + tx + tap % 3]);
        }
      }
      *(short8*)(Al + tid * 80 + i * 16) = v;
    }
  }
  __syncthreads();

  f32x4 acc[4][4];
  bf16x8 af[4], bfr[4];
#pragma unroll
  for (int m = 0; m < 4; ++m) {
    int pix = wm * 64 + m * 16 + l15;
    af[m] = *(const bf16x8*)(Al + pix * 80 + lq * 16);
  }
#pragma unroll
  for (int n = 0; n < 4; ++n)
    bfr[n] = *(const bf16x8*)(Bl + ((lq * 64 + n * 16 + l15) << 4));
#pragma unroll
  for (int m = 0; m < 4; ++m)
#pragma unroll
    for (int n = 0; n < 4; ++n) {
      f32x4 z = {0.f, 0.f, 0.f, 0.f};
      acc[m][n] = __builtin_amdgcn_mfma_f32_16x16x32_bf16(af[m], bfr[n], z, 0, 0, 0);
    }

  if constexpr (!POOL) {
    float* sbuf = (float*)lds;
    __syncthreads();
    for (int i = tid; i < 128; i += 256) sbuf[i] = 0.f;
    __syncthreads();
#pragma unroll
    for (int n = 0; n < 4; ++n) {
      float s1 = 0.f, s2 = 0.f;
#pragma unroll
      for (int m = 0; m < 4; ++m)
#pragma unroll
        for (int r = 0; r < 4; ++r) { float v = acc[m][n][r]; s1 += v; s2 += v * v; }
      s1 += __shfl_xor(s1, 16); s2 += __shfl_xor(s2, 16);
      s1 += __shfl_xor(s1, 32); s2 += __shfl_xor(s2, 32);
      if (lq == 0) {
        int cg = n * 16 + l15;
        atomicAdd(&sbuf[2 * cg], s1);
        atomicAdd(&sbuf[2 * cg + 1], s2);
      }
    }
    __syncthreads();
    if (tid < 128) atomicAdd(&sums[tid], sbuf[tid]);
  } else {
    float ssv[4], ssh[4];
#pragma unroll
    for (int n = 0; n < 4; ++n) {
      ssv[n] = ss[n * 16 + l15];
      ssh[n] = ss[64 + n * 16 + l15];
    }
#pragma unroll
    for (int m = 0; m < 4; m += 2)
#pragma unroll
      for (int n = 0; n < 4; ++n)
#pragma unroll
        for (int r0 = 0; r0 < 4; r0 += 2) {
          float a0 = fmaf(acc[m][n][r0], ssv[n], ssh[n]);
          float a1 = fmaf(acc[m][n][r0 + 1], ssv[n], ssh[n]);
          float b0 = fmaf(acc[m + 1][n][r0], ssv[n], ssh[n]);
          float b1 = fmaf(acc[m + 1][n][r0 + 1], ssv[n], ssh[n]);
          float v = fmaxf(fmaxf(fmaxf(a0, a1), fmaxf(b0, b1)), 0.f);
          int py = (ty0 >> 1) + ((wm * 4 + m) >> 1);
          int px = (tx0 >> 1) + ((lq * 4 + r0) >> 1);
          size_t idx = ((size_t)img * 256 + py * 16 + px) * 64 + n * 16 + l15;
          r1[idx] = v;
          r1b[idx] = f2bf(v);
        }
  }
}

__global__ void ss_k(const float* __restrict__ sums, const float* __restrict__ g,
                     const float* __restrict__ b, float* __restrict__ ss, int C, float invN) {
  int c = blockIdx.x * 64 + threadIdx.x;
  if (c < C) {
    float m = sums[2 * c] * invN;
    float var = sums[2 * c + 1] * invN - m * m;
    float sc = g[c] * rsqrtf(var + 1e-5f);
    ss[c] = sc;
    ss[C + c] = b[c] - m * sc;
  }
}

template<int C, int H>
__global__ __launch_bounds__(256) void bnpool_k(const u16* __restrict__ t, const float* __restrict__ ss,
                                                float* __restrict__ r, u16* __restrict__ rb) {
  constexpr int HP = H / 2, C4 = C / 4;
  int idx = blockIdx.x * 256 + threadIdx.x;
  int c4 = idx % C4, po = idx / C4;
  int xo = po % HP, t2 = po / HP;
  int yo = t2 % HP, img = t2 / HP;
  const u16* p0 = t + (((size_t)img * H + 2 * yo) * H + 2 * xo) * C + c4 * 4;
  u16x4 a = *(const u16x4*)p0, b = *(const u16x4*)(p0 + C);
  u16x4 c_ = *(const u16x4*)(p0 + H * C), d = *(const u16x4*)(p0 + H * C + C);
  f32x4 sc = *(const f32x4*)(ss + c4 * 4);
  f32x4 sh = *(const f32x4*)(ss + C + c4 * 4);
  f32x4 o;
#pragma unroll
  for (int j = 0; j < 4; ++j) {
    float v0 = fmaf(bf2f(a[j]), sc[j], sh[j]);
    float v1 = fmaf(bf2f(b[j]), sc[j], sh[j]);
    float v2 = fmaf(bf2f(c_[j]), sc[j], sh[j]);
    float v3 = fmaf(bf2f(d[j]), sc[j], sh[j]);
    o[j] = fmaxf(fmaxf(fmaxf(v0, v1), fmaxf(v2, v3)), 0.f);
  }
  *(f32x4*)(r + (size_t)idx * 4) = o;
  u16x4 ob;
#pragma unroll
  for (int j = 0; j < 4; ++j) ob[j] = f2bf(o[j]);
  *(u16x4*)(rb + (size_t)idx * 4) = ob;
}

extern "C" void kernel_launch(void* const* d_in, const int* in_sizes, int n_in,
                              void* d_out, int out_size, void* d_ws, size_t ws_size,
                              hipStream_t stream) {
  const float* x  = (const float*)d_in[0];
  const float* W1 = (const float*)d_in[1];
  const float* W2 = (const float*)d_in[2];
  const float* W3 = (const float*)d_in[3];
  const float* P2 = (const float*)d_in[4];
  const float* P3 = (const float*)d_in[5];
  const float* g1 = (const float*)d_in[6];
  const float* b1 = (const float*)d_in[7];
  const float* g2 = (const float*)d_in[8];
  const float* b2 = (const float*)d_in[9];
  const float* g3 = (const float*)d_in[10];
  const float* b3 = (const float*)d_in[11];

  char* w = (char*)d_ws;
  auto alloc = [&](size_t n) { char* p = w; w += (n + 255) & ~(size_t)255; return p; };
  float* r1  = (float*)alloc(16777216);  // NHWC [256,16,16,64]
  float* r2  = (float*)alloc(8388608);   // [256,8,8,128]
  float* r3  = (float*)alloc(4194304);   // [256,4,4,256]
  u16* r1b   = (u16*)alloc(8388608);
  u16* r2b   = (u16*)alloc(4194304);
  u16* r3b   = (u16*)alloc(2097152);
  u16* W2pk  = (u16*)alloc(147456);
  u16* W3pk  = (u16*)alloc(589824);
  u16* P2pk  = (u16*)alloc(147456);
  u16* P3pk  = (u16*)alloc(589824);
  u16* W1pk  = (u16*)alloc(4096);
  float* sums = (float*)alloc(3584);
  float* ssb  = (float*)alloc(3584);
  char* S = alloc(33554432);             // t2 16MB / t3 8MB / e1b 8MB / e2b 4MB
  u16* t2 = (u16*)S;
  u16* t3 = (u16*)S;
  u16* e1b = (u16*)S;
  u16* e2b = (u16*)(S + 8388608);

  hipMemsetAsync(sums, 0, 3584, stream);

  pack_k<64, 128, false><<<288, 256, 0, stream>>>(W2, W2pk);
  pack_k<128, 256, false><<<1152, 256, 0, stream>>>(W3, W3pk);
  pack_k<128, 64, true><<<288, 256, 0, stream>>>(P2, P2pk);
  pack_k<256, 128, true><<<1152, 256, 0, stream>>>(P3, P3pk);
  pack1_k<<<1, 256, 0, stream>>>(W1, W1pk);

  // ---- feed-forward ----
  c1_k<false><<<1024, 256, 0, stream>>>(x, W1pk, sums, nullptr, nullptr, nullptr);
  ss_k<<<1, 64, 0, stream>>>(sums, g1, b1, ssb, 64, 1.f / 262144.f);
  c1_k<true><<<1024, 256, 0, stream>>>(x, W1pk, nullptr, ssb, r1, r1b);

  ff2_k<<<512, 512, 0, stream>>>(r1b, W2pk, t2, sums + 128);
  ss_k<<<2, 64, 0, stream>>>(sums + 128, g2, b2, ssb + 128, 128, 1.f / 65536.f);
  bnpool_k<128, 16><<<2048, 256, 0, stream>>>(t2, ssb + 128, r2, r2b);

  ff3_k<<<256, 512, 0, stream>>>(r2b, W3pk, t3, sums + 384);
  ss_k<<<4, 64, 0, stream>>>(sums + 384, g3, b3, ssb + 384, 256, 1.f / 16384.f);
  bnpool_k<256, 8><<<1024, 256, 0, stream>>>(t3, ssb + 384, r3, r3b);

  // ---- predictive-coding iterations ----
  float* out  = (float*)d_out;
  float* out1 = out;
  float* out2 = out + 4194304;
  float* out3 = out + 6291456;
  for (int it = 0; it < 9; ++it) {
    ea_k<false><<<320, 512, 0, stream>>>(r2b, P2pk, r1, e1b, r3b, P3pk, r2, e2b, nullptr);
    pb_k<false><<<768, 512, 0, stream>>>(e1b, W2pk, r2, r2b, e2b, W3pk, r3, r3b, nullptr, nullptr);
  }
  // last iteration: fused NCHW output writes (replaces tr_k transposes)
  ea_k<true><<<320, 512, 0, stream>>>(r2b, P2pk, r1, e1b, r3b, P3pk, r2, e2b, out1);
  pb_k<true><<<768, 512, 0, stream>>>(e1b, W2pk, r2, r2b, e2b, W3pk, r3, r3b, out2, out3);
}